// Round 3
// baseline (838.127 us; speedup 1.0000x reference)
//
#include <hip/hip_runtime.h>
#include <math.h>

#define B 64
#define Lw 2048
#define Hd 1024
#define Vd 50257

// ws offsets (in floats)
#define WS_XH4    0          // packed [x;h] activations: 2048*64 = 131072
#define WS_GATES  131072     // gatesT [4096][64]        = 262144
#define WS_CAT4   393216     // packed [h1;context]      = 131072
#define WS_ENERGY 524288     // energies [64][2048]      = 131072
#define WS_PART   655360     // 16*64 partials * 1032    = 1056768
#define WS_MS     1712128    // per-b (m, s)             = 128
#define WS_CONCAT 1712256    // packed concat_out        = 65536

// d_out offsets (floats): output[B][V], h1[1][B][H], c1[1][B][H], attn[B][1][L]
#define OUT_H1   3216448
#define OUT_C1   3281984
#define OUT_ATTN 3347520

#define NCHUNK 16
#define LCHUNK 128
#define PSTRIDE 1032

__device__ __forceinline__ float sigm(float x) { return 1.f / (1.f + expf(-x)); }

// Force a wave-uniform pointer into SGPRs so the backend selects s_load
// (scalar cache) for W broadcasts instead of wave-uniform VMEM or LDS.
__device__ __forceinline__ const float* uniform_ptr(const float* p)
{
    unsigned long long v = (unsigned long long)p;
    unsigned int lo = __builtin_amdgcn_readfirstlane((unsigned int)v);
    unsigned int hi = __builtin_amdgcn_readfirstlane((unsigned int)(v >> 32));
    return (const float*)(((unsigned long long)hi << 32) | lo);
}

// ---------------- embed + pack [x ; h_prev] transposed: xh4[(k/4)*256 + b*4 + k%4]
__global__ void k_embed(const int* __restrict__ seq, const float* __restrict__ emb,
                        const float* __restrict__ h0, float* __restrict__ xh)
{
    int b = blockIdx.x;
    int t = threadIdx.x;               // handles h = t*4 .. t*4+3
    int tok = seq[b];
    float4 xv = *(const float4*)(emb + (size_t)tok * Hd + t * 4);
    float4 hv = *(const float4*)(h0 + (size_t)b * Hd + t * 4);
    ((float4*)xh)[t * B + b] = xv;            // k = t*4 (x part)
    ((float4*)xh)[(256 + t) * B + b] = hv;    // k = 1024 + t*4 (h part)
}

// ---------------- skinny GEMM, W broadcast from SGPRs (s_load via uniform addr)
// out[b, row] = act[b, :] . W[row, :] (+bias).  lane = b.
// Each wave owns ROWS consecutive rows; W row base is wave-uniform ->
// scalar loads; act is a coalesced per-lane float4 stream (L2-resident).
// MODE 0: gatesT store [row][B], bias1+bias2
// MODE 1: tanh, packed4 store (feeds next GEMM), bias1
// MODE 2: plain [b][row] store (d_out), bias1
template<int K1, int K2, int ROWS, int MODE>
__global__ void k_gemm(const float4* __restrict__ act,
                       const float* __restrict__ W1, const float* __restrict__ W2,
                       const float* __restrict__ b1, const float* __restrict__ b2,
                       int N, float* __restrict__ out, int ldout)
{
    int wave = threadIdx.x >> 6;
    int lane = threadIdx.x & 63;
    int r0 = (blockIdx.x * 4 + wave) * ROWS;
    if (r0 >= N) return;
    if (r0 > N - ROWS) r0 = N - ROWS;   // shift-down tail: overlapping waves
                                        // recompute identical rows (stores dup
                                        // identical values -> benign)

    const float* w1 = uniform_ptr(W1 + (size_t)r0 * K1);

    float acc[ROWS];
#pragma unroll
    for (int r = 0; r < ROWS; ++r) acc[r] = 0.f;

    for (int k4 = 0; k4 < K1 / 4; ++k4) {
        float4 a = act[k4 * B + lane];
#pragma unroll
        for (int r = 0; r < ROWS; ++r) {
            float4 w = *(const float4*)(w1 + (size_t)r * K1 + k4 * 4);  // s_load
            acc[r] += a.x * w.x + a.y * w.y + a.z * w.z + a.w * w.w;
        }
    }
    if constexpr (K2 > 0) {
        const float* w2 = uniform_ptr(W2 + (size_t)r0 * K2);
        for (int k4 = 0; k4 < K2 / 4; ++k4) {
            float4 a = act[(K1 / 4 + k4) * B + lane];
#pragma unroll
            for (int r = 0; r < ROWS; ++r) {
                float4 w = *(const float4*)(w2 + (size_t)r * K2 + k4 * 4);
                acc[r] += a.x * w.x + a.y * w.y + a.z * w.z + a.w * w.w;
            }
        }
    }

#pragma unroll
    for (int r = 0; r < ROWS; ++r) {
        int row = r0 + r;
        if constexpr (MODE == 0) {
            out[(size_t)row * B + lane] = acc[r] + b1[row] + b2[row];
        } else if constexpr (MODE == 1) {
            out[(row >> 2) * 256 + lane * 4 + (row & 3)] = tanhf(acc[r] + b1[row]);
        } else {
            out[(size_t)lane * ldout + row] = acc[r] + b1[row];
        }
    }
}

// ---------------- LSTM pointwise (PyTorch gate order i,f,g,o)
__global__ void k_pointwise(const float* __restrict__ gatesT, const float* __restrict__ c0,
                            float* __restrict__ h1o, float* __restrict__ c1o,
                            float* __restrict__ cat)
{
    int wave = threadIdx.x >> 6, lane = threadIdx.x & 63;
    int hh = blockIdx.x * 4 + wave;
    float gi = gatesT[(size_t)(0 * Hd + hh) * B + lane];
    float gf = gatesT[(size_t)(1 * Hd + hh) * B + lane];
    float gg = gatesT[(size_t)(2 * Hd + hh) * B + lane];
    float go = gatesT[(size_t)(3 * Hd + hh) * B + lane];
    float c  = c0[(size_t)lane * Hd + hh];
    float c1 = sigm(gf) * c + sigm(gi) * tanhf(gg);
    float h1 = sigm(go) * tanhf(c1);
    h1o[(size_t)lane * Hd + hh] = h1;
    c1o[(size_t)lane * Hd + hh] = c1;
    cat[(hh >> 2) * 256 + lane * 4 + (hh & 3)] = h1;   // packed, k = hh
}

// ---------------- fused energies + online-softmax context partials (one enc pass)
__global__ void k_attn_part(const float* __restrict__ enc, const float* __restrict__ h1,
                            float* __restrict__ energy, float* __restrict__ part)
{
    int chunk = blockIdx.x, b = blockIdx.y;
    int wave = threadIdx.x >> 6, lane = threadIdx.x & 63;

    float4 qv[4], ctx[4];
#pragma unroll
    for (int q = 0; q < 4; ++q) {
        qv[q] = *(const float4*)(h1 + (size_t)b * Hd + q * 256 + lane * 4);
        ctx[q] = make_float4(0.f, 0.f, 0.f, 0.f);
    }
    float m = -INFINITY, s = 0.f;

    for (int i = 0; i < LCHUNK / 4; ++i) {
        int l = chunk * LCHUNK + i * 4 + wave;
        const float* ep = enc + ((size_t)l * B + b) * Hd;
        float4 ev[4];
#pragma unroll
        for (int q = 0; q < 4; ++q) ev[q] = *(const float4*)(ep + q * 256 + lane * 4);
        float d = 0.f;
#pragma unroll
        for (int q = 0; q < 4; ++q)
            d += ev[q].x * qv[q].x + ev[q].y * qv[q].y + ev[q].z * qv[q].z + ev[q].w * qv[q].w;
#pragma unroll
        for (int off = 32; off >= 1; off >>= 1) d += __shfl_xor(d, off);
        if (lane == 0) energy[(size_t)b * Lw + l] = d;

        if (d > m) {                       // wave-uniform branch, rare after warmup
            float sc = expf(m - d);
            s *= sc;
#pragma unroll
            for (int q = 0; q < 4; ++q) {
                ctx[q].x *= sc; ctx[q].y *= sc; ctx[q].z *= sc; ctx[q].w *= sc;
            }
            m = d;
        }
        float w = expf(d - m);
        s += w;
#pragma unroll
        for (int q = 0; q < 4; ++q) {
            ctx[q].x += w * ev[q].x; ctx[q].y += w * ev[q].y;
            ctx[q].z += w * ev[q].z; ctx[q].w += w * ev[q].w;
        }
    }

    // combine the 4 waves of this block
    __shared__ float lctx[4][Hd];
    __shared__ float lms[4][2];
#pragma unroll
    for (int q = 0; q < 4; ++q)
        *(float4*)(&lctx[wave][q * 256 + lane * 4]) = ctx[q];
    if (lane == 0) { lms[wave][0] = m; lms[wave][1] = s; }
    __syncthreads();

    float mb = fmaxf(fmaxf(lms[0][0], lms[1][0]), fmaxf(lms[2][0], lms[3][0]));
    float sc0 = expf(lms[0][0] - mb), sc1 = expf(lms[1][0] - mb);
    float sc2 = expf(lms[2][0] - mb), sc3 = expf(lms[3][0] - mb);
    float sb = lms[0][1] * sc0 + lms[1][1] * sc1 + lms[2][1] * sc2 + lms[3][1] * sc3;

    int t = threadIdx.x;
    float* pb = part + (size_t)(chunk * B + b) * PSTRIDE;
    float4 a0 = *(float4*)(&lctx[0][t * 4]);
    float4 a1 = *(float4*)(&lctx[1][t * 4]);
    float4 a2 = *(float4*)(&lctx[2][t * 4]);
    float4 a3 = *(float4*)(&lctx[3][t * 4]);
    float4 v;
    v.x = a0.x * sc0 + a1.x * sc1 + a2.x * sc2 + a3.x * sc3;
    v.y = a0.y * sc0 + a1.y * sc1 + a2.y * sc2 + a3.y * sc3;
    v.z = a0.z * sc0 + a1.z * sc1 + a2.z * sc2 + a3.z * sc3;
    v.w = a0.w * sc0 + a1.w * sc1 + a2.w * sc2 + a3.w * sc3;
    *(float4*)(pb + t * 4) = v;
    if (t == 0) { pb[1024] = mb; pb[1025] = sb; }
}

// ---------------- merge chunk partials -> context (packed into cat second half) + (m,s)
__global__ void k_attn_combine(const float* __restrict__ part, float* __restrict__ cat,
                               float* __restrict__ ms)
{
    int b = blockIdx.x, t = threadIdx.x;
    float m = -INFINITY;
#pragma unroll
    for (int c = 0; c < NCHUNK; ++c)
        m = fmaxf(m, part[(size_t)(c * B + b) * PSTRIDE + 1024]);
    float s = 0.f, scl[NCHUNK];
#pragma unroll
    for (int c = 0; c < NCHUNK; ++c) {
        const float* pb = part + (size_t)(c * B + b) * PSTRIDE;
        scl[c] = expf(pb[1024] - m);
        s += pb[1025] * scl[c];
    }
    float4 v = make_float4(0.f, 0.f, 0.f, 0.f);
#pragma unroll
    for (int c = 0; c < NCHUNK; ++c) {
        float4 p = *(const float4*)(part + (size_t)(c * B + b) * PSTRIDE + t * 4);
        v.x += p.x * scl[c]; v.y += p.y * scl[c]; v.z += p.z * scl[c]; v.w += p.w * scl[c];
    }
    float inv = 1.f / s;
    v.x *= inv; v.y *= inv; v.z *= inv; v.w *= inv;
    ((float4*)cat)[(256 + t) * B + b] = v;      // k = 1024 + t*4 (context part)
    if (t == 0) { ms[b * 2] = m; ms[b * 2 + 1] = s; }
}

// ---------------- attn output normalize
__global__ void k_attn_norm(const float* __restrict__ energy, const float* __restrict__ ms,
                            float* __restrict__ attn)
{
    int idx = blockIdx.x * blockDim.x + threadIdx.x;   // [0, 131072)
    int b = idx >> 11;
    float m = ms[b * 2], s = ms[b * 2 + 1];
    attn[idx] = expf(energy[idx] - m) / s;
}

extern "C" void kernel_launch(void* const* d_in, const int* in_sizes, int n_in,
                              void* d_out, int out_size, void* d_ws, size_t ws_size,
                              hipStream_t stream)
{
    const int*   seq    = (const int*)d_in[0];
    const float* enc    = (const float*)d_in[1];
    const float* h0     = (const float*)d_in[2];
    const float* c0     = (const float*)d_in[3];
    const float* emb    = (const float*)d_in[4];
    const float* W_ih   = (const float*)d_in[5];
    const float* W_hh   = (const float*)d_in[6];
    const float* b_ih   = (const float*)d_in[7];
    const float* b_hh   = (const float*)d_in[8];
    const float* W_cat  = (const float*)d_in[9];
    const float* b_cat  = (const float*)d_in[10];
    const float* W_out  = (const float*)d_in[11];
    const float* b_out  = (const float*)d_in[12];
    float* out = (float*)d_out;
    float* ws  = (float*)d_ws;

    float* xh     = ws + WS_XH4;
    float* gatesT = ws + WS_GATES;
    float* cat    = ws + WS_CAT4;
    float* energy = ws + WS_ENERGY;
    float* part   = ws + WS_PART;
    float* ms     = ws + WS_MS;
    float* conc   = ws + WS_CONCAT;

    k_embed<<<B, 256, 0, stream>>>(seq, emb, h0, xh);
    // gates = [x;h] @ [W_ih | W_hh]^T + b_ih + b_hh : N=4096, K=1024+1024
    // ROWS=4 -> 16 rows/block, 256 blocks
    k_gemm<1024, 1024, 4, 0><<<256, 256, 0, stream>>>(
        (const float4*)xh, W_ih, W_hh, b_ih, b_hh, 4 * Hd, gatesT, 0);
    k_pointwise<<<256, 256, 0, stream>>>(gatesT, c0, out + OUT_H1, out + OUT_C1, cat);
    k_attn_part<<<dim3(NCHUNK, B), 256, 0, stream>>>(enc, out + OUT_H1, energy, part);
    k_attn_combine<<<B, 256, 0, stream>>>(part, cat, ms);
    k_attn_norm<<<512, 256, 0, stream>>>(energy, ms, out + OUT_ATTN);
    // concat_out = tanh([h1;ctx] @ W_concat^T + b) : N=1024, K=2048
    // ROWS=2 -> 8 rows/block, 128 blocks
    k_gemm<2048, 0, 2, 1><<<128, 256, 0, stream>>>(
        (const float4*)cat, W_cat, nullptr, b_cat, nullptr, Hd, conc, 0);
    // output = concat_out @ W_out^T + b_out : N=50257, K=1024
    // ROWS=8 -> 32 rows/block, ceil(50257/32)=1571 blocks
    k_gemm<1024, 0, 8, 2><<<1571, 256, 0, stream>>>(
        (const float4*)conc, W_out, nullptr, b_out, nullptr, Vd, out, Vd);
}

// Round 4
// 421.796 us; speedup vs baseline: 1.9870x; 1.9870x over previous
//
#include <hip/hip_runtime.h>
#include <math.h>

#define B 64
#define Lw 2048
#define Hd 1024
#define Vd 50257

// ws offsets (in floats)
#define WS_XH4    0          // packed [x;h] activations: 2048*64 = 131072
#define WS_GATES  131072     // gatesT [4096][64]        = 262144
#define WS_CAT4   393216     // packed [h1;context]      = 131072
#define WS_ENERGY 524288     // energies [64][2048]      = 131072
#define WS_PART   655360     // 16*64 partials * 1032    = 1056768
#define WS_MS     1712128    // per-b (m, s)             = 128
#define WS_CONCAT 1712256    // packed concat_out        = 65536

// d_out offsets (floats): output[B][V], h1[1][B][H], c1[1][B][H], attn[B][1][L]
#define OUT_H1   3216448
#define OUT_C1   3281984
#define OUT_ATTN 3347520

#define NCHUNK 16
#define LCHUNK 128
#define PSTRIDE 1032

typedef float sf16 __attribute__((ext_vector_type(16)));

__device__ __forceinline__ float sigm(float x) { return 1.f / (1.f + expf(-x)); }

__device__ __forceinline__ const float* uniform_ptr(const float* p)
{
    unsigned long long v = (unsigned long long)p;
    unsigned int lo = __builtin_amdgcn_readfirstlane((unsigned int)v);
    unsigned int hi = __builtin_amdgcn_readfirstlane((unsigned int)(v >> 32));
    return (const float*)(((unsigned long long)hi << 32) | lo);
}

// ---------------- embed + pack [x ; h_prev] transposed: xh4[(k/4)*256 + b*4 + k%4]
__global__ void k_embed(const int* __restrict__ seq, const float* __restrict__ emb,
                        const float* __restrict__ h0, float* __restrict__ xh)
{
    int b = blockIdx.x;
    int t = threadIdx.x;               // handles h = t*4 .. t*4+3
    int tok = seq[b];
    float4 xv = *(const float4*)(emb + (size_t)tok * Hd + t * 4);
    float4 hv = *(const float4*)(h0 + (size_t)b * Hd + t * 4);
    ((float4*)xh)[t * B + b] = xv;            // k = t*4 (x part)
    ((float4*)xh)[(256 + t) * B + b] = hv;    // k = 1024 + t*4 (h part)
}

// ---------------- skinny GEMM: W broadcast via explicit s_load_dwordx16 (SMEM pipe)
// out[b, row] = act[b, :] . W[row, :] (+bias).  lane = b; wave owns ROWS rows.
// W rows stream HBM->K$->SGPRs (64B/inst, parallel to VALU); act is a coalesced
// per-lane float4 stream reused ROWS times per load.
// MODE 0: gatesT store [row][B], bias1+bias2
// MODE 1: tanh, packed4 store (feeds next GEMM), bias1
// MODE 2: plain [b][row] store (d_out), bias1
template<int K, bool TWO, int ROWS, int GR, int MODE>
__global__ void k_sgemm(const float4* __restrict__ act,
                        const float* __restrict__ W1, const float* __restrict__ W2,
                        const float* __restrict__ b1, const float* __restrict__ b2,
                        int N, float* __restrict__ out, int ldout)
{
    constexpr int NG = ROWS / GR;
    static_assert(ROWS % GR == 0 && K % 16 == 0, "shape");

    int wave = threadIdx.x >> 6;
    int lane = threadIdx.x & 63;
    int r0 = (blockIdx.x * 4 + wave) * ROWS;
    if (r0 >= N) return;
    if (r0 > N - ROWS) r0 = N - ROWS;   // shift-down tail (dup stores benign)
    r0 = __builtin_amdgcn_readfirstlane(r0);

    float acc[ROWS];
#pragma unroll
    for (int r = 0; r < ROWS; ++r) acc[r] = 0.f;

#pragma unroll 1
    for (int half = 0; half < (TWO ? 2 : 1); ++half) {
        const float* Wp = uniform_ptr((half ? W2 : W1) + (size_t)r0 * K);
#pragma unroll 1
        for (int kc = 0; kc < K; kc += 16) {
            int k4 = ((TWO ? half * K : 0) + kc) >> 2;
            float4 av0 = act[(k4 + 0) * B + lane];
            float4 av1 = act[(k4 + 1) * B + lane];
            float4 av2 = act[(k4 + 2) * B + lane];
            float4 av3 = act[(k4 + 3) * B + lane];
#pragma unroll
            for (int g = 0; g < NG; ++g) {
                sf16 w[GR];
#pragma unroll
                for (int r = 0; r < GR; ++r) {
                    int off = ((g * GR + r) * K + kc) * 4;   // uniform byte offset
                    asm volatile("s_load_dwordx16 %0, %1, %2"
                                 : "=s"(w[r]) : "s"(Wp), "s"(off));
                }
                if constexpr (GR == 4)
                    asm volatile("s_waitcnt lgkmcnt(0)"
                                 : "+s"(w[0]), "+s"(w[1]), "+s"(w[2]), "+s"(w[3]));
                else if constexpr (GR == 2)
                    asm volatile("s_waitcnt lgkmcnt(0)" : "+s"(w[0]), "+s"(w[1]));
                else
                    asm volatile("s_waitcnt lgkmcnt(0)" : "+s"(w[0]));
                __builtin_amdgcn_sched_barrier(0);
#pragma unroll
                for (int r = 0; r < GR; ++r) {
                    float* A = acc + g * GR + r;
                    *A += w[r][0]  * av0.x; *A += w[r][1]  * av0.y;
                    *A += w[r][2]  * av0.z; *A += w[r][3]  * av0.w;
                    *A += w[r][4]  * av1.x; *A += w[r][5]  * av1.y;
                    *A += w[r][6]  * av1.z; *A += w[r][7]  * av1.w;
                    *A += w[r][8]  * av2.x; *A += w[r][9]  * av2.y;
                    *A += w[r][10] * av2.z; *A += w[r][11] * av2.w;
                    *A += w[r][12] * av3.x; *A += w[r][13] * av3.y;
                    *A += w[r][14] * av3.z; *A += w[r][15] * av3.w;
                }
            }
        }
    }

#pragma unroll
    for (int r = 0; r < ROWS; ++r) {
        int row = r0 + r;
        if constexpr (MODE == 0) {
            out[(size_t)row * B + lane] = acc[r] + b1[row] + b2[row];
        } else if constexpr (MODE == 1) {
            out[(row >> 2) * 256 + lane * 4 + (row & 3)] = tanhf(acc[r] + b1[row]);
        } else {
            out[(size_t)lane * ldout + row] = acc[r] + b1[row];
        }
    }
}

// ---------------- LSTM pointwise (PyTorch gate order i,f,g,o)
__global__ void k_pointwise(const float* __restrict__ gatesT, const float* __restrict__ c0,
                            float* __restrict__ h1o, float* __restrict__ c1o,
                            float* __restrict__ cat)
{
    int wave = threadIdx.x >> 6, lane = threadIdx.x & 63;
    int hh = blockIdx.x * 4 + wave;
    float gi = gatesT[(size_t)(0 * Hd + hh) * B + lane];
    float gf = gatesT[(size_t)(1 * Hd + hh) * B + lane];
    float gg = gatesT[(size_t)(2 * Hd + hh) * B + lane];
    float go = gatesT[(size_t)(3 * Hd + hh) * B + lane];
    float c  = c0[(size_t)lane * Hd + hh];
    float c1 = sigm(gf) * c + sigm(gi) * tanhf(gg);
    float h1 = sigm(go) * tanhf(c1);
    h1o[(size_t)lane * Hd + hh] = h1;
    c1o[(size_t)lane * Hd + hh] = c1;
    cat[(hh >> 2) * 256 + lane * 4 + (hh & 3)] = h1;   // packed, k = hh
}

// ---------------- fused energies + online-softmax context partials (one enc pass)
__global__ void k_attn_part(const float* __restrict__ enc, const float* __restrict__ h1,
                            float* __restrict__ energy, float* __restrict__ part)
{
    int chunk = blockIdx.x, b = blockIdx.y;
    int wave = threadIdx.x >> 6, lane = threadIdx.x & 63;

    float4 qv[4], ctx[4];
#pragma unroll
    for (int q = 0; q < 4; ++q) {
        qv[q] = *(const float4*)(h1 + (size_t)b * Hd + q * 256 + lane * 4);
        ctx[q] = make_float4(0.f, 0.f, 0.f, 0.f);
    }
    float m = -INFINITY, s = 0.f;

    for (int i = 0; i < LCHUNK / 4; ++i) {
        int l = chunk * LCHUNK + i * 4 + wave;
        const float* ep = enc + ((size_t)l * B + b) * Hd;
        float4 ev[4];
#pragma unroll
        for (int q = 0; q < 4; ++q) ev[q] = *(const float4*)(ep + q * 256 + lane * 4);
        float d = 0.f;
#pragma unroll
        for (int q = 0; q < 4; ++q)
            d += ev[q].x * qv[q].x + ev[q].y * qv[q].y + ev[q].z * qv[q].z + ev[q].w * qv[q].w;
#pragma unroll
        for (int off = 32; off >= 1; off >>= 1) d += __shfl_xor(d, off);
        if (lane == 0) energy[(size_t)b * Lw + l] = d;

        if (d > m) {                       // wave-uniform branch, rare after warmup
            float sc = expf(m - d);
            s *= sc;
#pragma unroll
            for (int q = 0; q < 4; ++q) {
                ctx[q].x *= sc; ctx[q].y *= sc; ctx[q].z *= sc; ctx[q].w *= sc;
            }
            m = d;
        }
        float w = expf(d - m);
        s += w;
#pragma unroll
        for (int q = 0; q < 4; ++q) {
            ctx[q].x += w * ev[q].x; ctx[q].y += w * ev[q].y;
            ctx[q].z += w * ev[q].z; ctx[q].w += w * ev[q].w;
        }
    }

    // combine the 4 waves of this block
    __shared__ float lctx[4][Hd];
    __shared__ float lms[4][2];
#pragma unroll
    for (int q = 0; q < 4; ++q)
        *(float4*)(&lctx[wave][q * 256 + lane * 4]) = ctx[q];
    if (lane == 0) { lms[wave][0] = m; lms[wave][1] = s; }
    __syncthreads();

    float mb = fmaxf(fmaxf(lms[0][0], lms[1][0]), fmaxf(lms[2][0], lms[3][0]));
    float sc0 = expf(lms[0][0] - mb), sc1 = expf(lms[1][0] - mb);
    float sc2 = expf(lms[2][0] - mb), sc3 = expf(lms[3][0] - mb);
    float sb = lms[0][1] * sc0 + lms[1][1] * sc1 + lms[2][1] * sc2 + lms[3][1] * sc3;

    int t = threadIdx.x;
    float* pb = part + (size_t)(chunk * B + b) * PSTRIDE;
    float4 a0 = *(float4*)(&lctx[0][t * 4]);
    float4 a1 = *(float4*)(&lctx[1][t * 4]);
    float4 a2 = *(float4*)(&lctx[2][t * 4]);
    float4 a3 = *(float4*)(&lctx[3][t * 4]);
    float4 v;
    v.x = a0.x * sc0 + a1.x * sc1 + a2.x * sc2 + a3.x * sc3;
    v.y = a0.y * sc0 + a1.y * sc1 + a2.y * sc2 + a3.y * sc3;
    v.z = a0.z * sc0 + a1.z * sc1 + a2.z * sc2 + a3.z * sc3;
    v.w = a0.w * sc0 + a1.w * sc1 + a2.w * sc2 + a3.w * sc3;
    *(float4*)(pb + t * 4) = v;
    if (t == 0) { pb[1024] = mb; pb[1025] = sb; }
}

// ---------------- merge chunk partials -> context (packed into cat second half) + (m,s)
__global__ void k_attn_combine(const float* __restrict__ part, float* __restrict__ cat,
                               float* __restrict__ ms)
{
    int b = blockIdx.x, t = threadIdx.x;
    float m = -INFINITY;
#pragma unroll
    for (int c = 0; c < NCHUNK; ++c)
        m = fmaxf(m, part[(size_t)(c * B + b) * PSTRIDE + 1024]);
    float s = 0.f, scl[NCHUNK];
#pragma unroll
    for (int c = 0; c < NCHUNK; ++c) {
        const float* pb = part + (size_t)(c * B + b) * PSTRIDE;
        scl[c] = expf(pb[1024] - m);
        s += pb[1025] * scl[c];
    }
    float4 v = make_float4(0.f, 0.f, 0.f, 0.f);
#pragma unroll
    for (int c = 0; c < NCHUNK; ++c) {
        float4 p = *(const float4*)(part + (size_t)(c * B + b) * PSTRIDE + t * 4);
        v.x += p.x * scl[c]; v.y += p.y * scl[c]; v.z += p.z * scl[c]; v.w += p.w * scl[c];
    }
    float inv = 1.f / s;
    v.x *= inv; v.y *= inv; v.z *= inv; v.w *= inv;
    ((float4*)cat)[(256 + t) * B + b] = v;      // k = 1024 + t*4 (context part)
    if (t == 0) { ms[b * 2] = m; ms[b * 2 + 1] = s; }
}

// ---------------- attn output normalize
__global__ void k_attn_norm(const float* __restrict__ energy, const float* __restrict__ ms,
                            float* __restrict__ attn)
{
    int idx = blockIdx.x * blockDim.x + threadIdx.x;   // [0, 131072)
    int b = idx >> 11;
    float m = ms[b * 2], s = ms[b * 2 + 1];
    attn[idx] = expf(energy[idx] - m) / s;
}

extern "C" void kernel_launch(void* const* d_in, const int* in_sizes, int n_in,
                              void* d_out, int out_size, void* d_ws, size_t ws_size,
                              hipStream_t stream)
{
    const int*   seq    = (const int*)d_in[0];
    const float* enc    = (const float*)d_in[1];
    const float* h0     = (const float*)d_in[2];
    const float* c0     = (const float*)d_in[3];
    const float* emb    = (const float*)d_in[4];
    const float* W_ih   = (const float*)d_in[5];
    const float* W_hh   = (const float*)d_in[6];
    const float* b_ih   = (const float*)d_in[7];
    const float* b_hh   = (const float*)d_in[8];
    const float* W_cat  = (const float*)d_in[9];
    const float* b_cat  = (const float*)d_in[10];
    const float* W_out  = (const float*)d_in[11];
    const float* b_out  = (const float*)d_in[12];
    float* out = (float*)d_out;
    float* ws  = (float*)d_ws;

    float* xh     = ws + WS_XH4;
    float* gatesT = ws + WS_GATES;
    float* cat    = ws + WS_CAT4;
    float* energy = ws + WS_ENERGY;
    float* part   = ws + WS_PART;
    float* ms     = ws + WS_MS;
    float* conc   = ws + WS_CONCAT;

    k_embed<<<B, 256, 0, stream>>>(seq, emb, h0, xh);
    // gates = [x;h] @ [W_ih | W_hh]^T + b_ih + b_hh : N=4096, K=1024(+1024)
    // ROWS=2, GR=2 -> 8 rows/block, 512 blocks (2048 waves = 2/SIMD)
    k_sgemm<1024, true, 2, 2, 0><<<512, 256, 0, stream>>>(
        (const float4*)xh, W_ih, W_hh, b_ih, b_hh, 4 * Hd, gatesT, 0);
    k_pointwise<<<256, 256, 0, stream>>>(gatesT, c0, out + OUT_H1, out + OUT_C1, cat);
    k_attn_part<<<dim3(NCHUNK, B), 256, 0, stream>>>(enc, out + OUT_H1, energy, part);
    k_attn_combine<<<B, 256, 0, stream>>>(part, cat, ms);
    k_attn_norm<<<512, 256, 0, stream>>>(energy, ms, out + OUT_ATTN);
    // concat_out = tanh([h1;ctx] @ W_concat^T + b) : N=1024, K=2048
    // ROWS=2, GR=2 -> 8 rows/block, 128 blocks
    k_sgemm<2048, false, 2, 2, 1><<<128, 256, 0, stream>>>(
        (const float4*)cat, W_cat, nullptr, b_cat, nullptr, Hd, conc, 0);
    // output = concat_out @ W_out^T + b_out : N=50257, K=1024
    // ROWS=8, GR=4 -> 32 rows/block, ceil(50257/32)=1571 blocks (~6 waves/SIMD)
    k_sgemm<1024, false, 8, 4, 2><<<1571, 256, 0, stream>>>(
        (const float4*)conc, W_out, nullptr, b_out, nullptr, Vd, out, Vd);
}

// Round 5
// 377.832 us; speedup vs baseline: 2.2183x; 1.1164x over previous
//
#include <hip/hip_runtime.h>
#include <math.h>

#define B 64
#define Lw 2048
#define Hd 1024
#define Vd 50257

// ws offsets (in floats)
#define WS_XH4    0          // packed [x;h] activations: 2048*64 = 131072
#define WS_GATES  131072     // gatesT [4096][64]        = 262144
#define WS_CAT4   393216     // packed [h1;context]      = 131072
#define WS_ENERGY 524288     // energies [64][2048]      = 131072
#define WS_PART   655360     // 16*64 partials * 1032    = 1056768
#define WS_MS     1712128    // per-b (m, s)             = 128
#define WS_CONCAT 1712256    // concat_out bf16-packed [128][64][8] = 65536 bf16 = 32768 floats

// d_out offsets (floats): output[B][V], h1[1][B][H], c1[1][B][H], attn[B][1][L]
#define OUT_H1   3216448
#define OUT_C1   3281984
#define OUT_ATTN 3347520

#define NCHUNK 16
#define LCHUNK 128
#define PSTRIDE 1032

typedef float sf16 __attribute__((ext_vector_type(16)));
typedef __bf16 bf16x8 __attribute__((ext_vector_type(8)));
typedef float f32x4 __attribute__((ext_vector_type(4)));

__device__ __forceinline__ float sigm(float x) { return 1.f / (1.f + expf(-x)); }

__device__ __forceinline__ const float* uniform_ptr(const float* p)
{
    unsigned long long v = (unsigned long long)p;
    unsigned int lo = __builtin_amdgcn_readfirstlane((unsigned int)v);
    unsigned int hi = __builtin_amdgcn_readfirstlane((unsigned int)(v >> 32));
    return (const float*)(((unsigned long long)hi << 32) | lo);
}

// ---------------- embed + pack [x ; h_prev] transposed: xh4[(k/4)*256 + b*4 + k%4]
__global__ void k_embed(const int* __restrict__ seq, const float* __restrict__ emb,
                        const float* __restrict__ h0, float* __restrict__ xh)
{
    int b = blockIdx.x;
    int t = threadIdx.x;               // handles h = t*4 .. t*4+3
    int tok = seq[b];
    float4 xv = *(const float4*)(emb + (size_t)tok * Hd + t * 4);
    float4 hv = *(const float4*)(h0 + (size_t)b * Hd + t * 4);
    ((float4*)xh)[t * B + b] = xv;            // k = t*4 (x part)
    ((float4*)xh)[(256 + t) * B + b] = hv;    // k = 1024 + t*4 (h part)
}

// ---------------- skinny GEMM: W broadcast via explicit s_load_dwordx16 (SMEM pipe)
// out[b, row] = act[b, :] . W[row, :] (+bias).  lane = b; wave owns ROWS rows.
// MODE 0: gatesT store [row][B], bias1+bias2
// MODE 1: tanh -> bf16 MFMA-fragment pack [row/8][lane][row%8], bias1
template<int K, bool TWO, int ROWS, int GR, int MODE>
__global__ void k_sgemm(const float4* __restrict__ act,
                        const float* __restrict__ W1, const float* __restrict__ W2,
                        const float* __restrict__ b1, const float* __restrict__ b2,
                        int N, float* __restrict__ out, int ldout)
{
    constexpr int NG = ROWS / GR;
    static_assert(ROWS % GR == 0 && K % 16 == 0, "shape");

    int wave = threadIdx.x >> 6;
    int lane = threadIdx.x & 63;
    int r0 = (blockIdx.x * 4 + wave) * ROWS;
    if (r0 >= N) return;
    if (r0 > N - ROWS) r0 = N - ROWS;   // shift-down tail (dup stores benign)
    r0 = __builtin_amdgcn_readfirstlane(r0);

    float acc[ROWS];
#pragma unroll
    for (int r = 0; r < ROWS; ++r) acc[r] = 0.f;

#pragma unroll 1
    for (int half = 0; half < (TWO ? 2 : 1); ++half) {
        const float* Wp = uniform_ptr((half ? W2 : W1) + (size_t)r0 * K);
#pragma unroll 1
        for (int kc = 0; kc < K; kc += 16) {
            int k4 = ((TWO ? half * K : 0) + kc) >> 2;
            float4 av0 = act[(k4 + 0) * B + lane];
            float4 av1 = act[(k4 + 1) * B + lane];
            float4 av2 = act[(k4 + 2) * B + lane];
            float4 av3 = act[(k4 + 3) * B + lane];
#pragma unroll
            for (int g = 0; g < NG; ++g) {
                sf16 w[GR];
#pragma unroll
                for (int r = 0; r < GR; ++r) {
                    int off = ((g * GR + r) * K + kc) * 4;   // uniform byte offset
                    asm volatile("s_load_dwordx16 %0, %1, %2"
                                 : "=s"(w[r]) : "s"(Wp), "s"(off));
                }
                if constexpr (GR == 4)
                    asm volatile("s_waitcnt lgkmcnt(0)"
                                 : "+s"(w[0]), "+s"(w[1]), "+s"(w[2]), "+s"(w[3]));
                else if constexpr (GR == 2)
                    asm volatile("s_waitcnt lgkmcnt(0)" : "+s"(w[0]), "+s"(w[1]));
                else
                    asm volatile("s_waitcnt lgkmcnt(0)" : "+s"(w[0]));
                __builtin_amdgcn_sched_barrier(0);
#pragma unroll
                for (int r = 0; r < GR; ++r) {
                    float* A = acc + g * GR + r;
                    *A += w[r][0]  * av0.x; *A += w[r][1]  * av0.y;
                    *A += w[r][2]  * av0.z; *A += w[r][3]  * av0.w;
                    *A += w[r][4]  * av1.x; *A += w[r][5]  * av1.y;
                    *A += w[r][6]  * av1.z; *A += w[r][7]  * av1.w;
                    *A += w[r][8]  * av2.x; *A += w[r][9]  * av2.y;
                    *A += w[r][10] * av2.z; *A += w[r][11] * av2.w;
                    *A += w[r][12] * av3.x; *A += w[r][13] * av3.y;
                    *A += w[r][14] * av3.z; *A += w[r][15] * av3.w;
                }
            }
        }
    }

#pragma unroll
    for (int r = 0; r < ROWS; ++r) {
        int row = r0 + r;
        if constexpr (MODE == 0) {
            out[(size_t)row * B + lane] = acc[r] + b1[row] + b2[row];
        } else {
            // bf16 MFMA A-fragment pack: [row/8][m=lane][row%8]
            __bf16* bp = (__bf16*)out;
            bp[(row >> 3) * 512 + lane * 8 + (row & 7)] =
                (__bf16)tanhf(acc[r] + b1[row]);
        }
    }
    (void)ldout;
}

// ---------------- vocab projection via bf16 MFMA 16x16x32
// C[b=64][v] = A[64][1024] . W[v][1024]^T + bias; one wave: 16 v-rows x 64 b.
// A pre-packed bf16 [kb=128][m=64][8]; W converted fp32->bf16 in-register.
__global__ void k_vocab_mfma(const __bf16* __restrict__ apack,
                             const float* __restrict__ W,
                             const float* __restrict__ bias,
                             float* __restrict__ out)
{
    int wave = threadIdx.x >> 6;
    int lane = threadIdx.x & 63;
    int n0 = (blockIdx.x * 4 + wave) * 16;
    if (n0 > Vd - 16) n0 = Vd - 16;        // tail shift-down (dup writes benign)

    int nl = n0 + (lane & 15);             // this lane's W row (B-frag col)
    int kq = lane >> 4;                    // k-quarter
    const float* wp = W + (size_t)nl * Hd + kq * 8;
    const __bf16* ap = apack + (size_t)(lane & 15) * 8;

    f32x4 acc[4] = {{0.f,0.f,0.f,0.f},{0.f,0.f,0.f,0.f},
                    {0.f,0.f,0.f,0.f},{0.f,0.f,0.f,0.f}};

#pragma unroll 4
    for (int k0 = 0; k0 < Hd; k0 += 32) {
        float4 w0 = *(const float4*)(wp + k0);
        float4 w1 = *(const float4*)(wp + k0 + 4);
        bf16x8 bfrag;
        bfrag[0] = (__bf16)w0.x; bfrag[1] = (__bf16)w0.y;
        bfrag[2] = (__bf16)w0.z; bfrag[3] = (__bf16)w0.w;
        bfrag[4] = (__bf16)w1.x; bfrag[5] = (__bf16)w1.y;
        bfrag[6] = (__bf16)w1.z; bfrag[7] = (__bf16)w1.w;
        int kb = (k0 >> 3) + kq;           // k-block of 8
#pragma unroll
        for (int mt = 0; mt < 4; ++mt) {
            bf16x8 afrag = *(const bf16x8*)(ap + (size_t)kb * 512 + mt * 128);
            acc[mt] = __builtin_amdgcn_mfma_f32_16x16x32_bf16(afrag, bfrag, acc[mt], 0, 0, 0);
        }
    }

    float bv = bias[nl];
#pragma unroll
    for (int mt = 0; mt < 4; ++mt)
#pragma unroll
        for (int r = 0; r < 4; ++r) {
            int m = mt * 16 + (lane >> 4) * 4 + r;   // batch (C/D row)
            out[(size_t)m * Vd + nl] = acc[mt][r] + bv;
        }
}

// ---------------- LSTM pointwise (PyTorch gate order i,f,g,o)
__global__ void k_pointwise(const float* __restrict__ gatesT, const float* __restrict__ c0,
                            float* __restrict__ h1o, float* __restrict__ c1o,
                            float* __restrict__ cat)
{
    int wave = threadIdx.x >> 6, lane = threadIdx.x & 63;
    int hh = blockIdx.x * 4 + wave;
    float gi = gatesT[(size_t)(0 * Hd + hh) * B + lane];
    float gf = gatesT[(size_t)(1 * Hd + hh) * B + lane];
    float gg = gatesT[(size_t)(2 * Hd + hh) * B + lane];
    float go = gatesT[(size_t)(3 * Hd + hh) * B + lane];
    float c  = c0[(size_t)lane * Hd + hh];
    float c1 = sigm(gf) * c + sigm(gi) * tanhf(gg);
    float h1 = sigm(go) * tanhf(c1);
    h1o[(size_t)lane * Hd + hh] = h1;
    c1o[(size_t)lane * Hd + hh] = c1;
    cat[(hh >> 2) * 256 + lane * 4 + (hh & 3)] = h1;   // packed, k = hh
}

// ---------------- fused energies + online-softmax context partials (one enc pass)
__global__ void k_attn_part(const float* __restrict__ enc, const float* __restrict__ h1,
                            float* __restrict__ energy, float* __restrict__ part)
{
    int chunk = blockIdx.x, b = blockIdx.y;
    int wave = threadIdx.x >> 6, lane = threadIdx.x & 63;

    float4 qv[4], ctx[4];
#pragma unroll
    for (int q = 0; q < 4; ++q) {
        qv[q] = *(const float4*)(h1 + (size_t)b * Hd + q * 256 + lane * 4);
        ctx[q] = make_float4(0.f, 0.f, 0.f, 0.f);
    }
    float m = -INFINITY, s = 0.f;

    for (int i = 0; i < LCHUNK / 4; ++i) {
        int l = chunk * LCHUNK + i * 4 + wave;
        const float* ep = enc + ((size_t)l * B + b) * Hd;
        float4 ev[4];
#pragma unroll
        for (int q = 0; q < 4; ++q) ev[q] = *(const float4*)(ep + q * 256 + lane * 4);
        float d = 0.f;
#pragma unroll
        for (int q = 0; q < 4; ++q)
            d += ev[q].x * qv[q].x + ev[q].y * qv[q].y + ev[q].z * qv[q].z + ev[q].w * qv[q].w;
#pragma unroll
        for (int off = 32; off >= 1; off >>= 1) d += __shfl_xor(d, off);
        if (lane == 0) energy[(size_t)b * Lw + l] = d;

        if (d > m) {                       // wave-uniform branch, rare after warmup
            float sc = expf(m - d);
            s *= sc;
#pragma unroll
            for (int q = 0; q < 4; ++q) {
                ctx[q].x *= sc; ctx[q].y *= sc; ctx[q].z *= sc; ctx[q].w *= sc;
            }
            m = d;
        }
        float w = expf(d - m);
        s += w;
#pragma unroll
        for (int q = 0; q < 4; ++q) {
            ctx[q].x += w * ev[q].x; ctx[q].y += w * ev[q].y;
            ctx[q].z += w * ev[q].z; ctx[q].w += w * ev[q].w;
        }
    }

    // combine the 4 waves of this block
    __shared__ float lctx[4][Hd];
    __shared__ float lms[4][2];
#pragma unroll
    for (int q = 0; q < 4; ++q)
        *(float4*)(&lctx[wave][q * 256 + lane * 4]) = ctx[q];
    if (lane == 0) { lms[wave][0] = m; lms[wave][1] = s; }
    __syncthreads();

    float mb = fmaxf(fmaxf(lms[0][0], lms[1][0]), fmaxf(lms[2][0], lms[3][0]));
    float sc0 = expf(lms[0][0] - mb), sc1 = expf(lms[1][0] - mb);
    float sc2 = expf(lms[2][0] - mb), sc3 = expf(lms[3][0] - mb);
    float sb = lms[0][1] * sc0 + lms[1][1] * sc1 + lms[2][1] * sc2 + lms[3][1] * sc3;

    int t = threadIdx.x;
    float* pb = part + (size_t)(chunk * B + b) * PSTRIDE;
    float4 a0 = *(float4*)(&lctx[0][t * 4]);
    float4 a1 = *(float4*)(&lctx[1][t * 4]);
    float4 a2 = *(float4*)(&lctx[2][t * 4]);
    float4 a3 = *(float4*)(&lctx[3][t * 4]);
    float4 v;
    v.x = a0.x * sc0 + a1.x * sc1 + a2.x * sc2 + a3.x * sc3;
    v.y = a0.y * sc0 + a1.y * sc1 + a2.y * sc2 + a3.y * sc3;
    v.z = a0.z * sc0 + a1.z * sc1 + a2.z * sc2 + a3.z * sc3;
    v.w = a0.w * sc0 + a1.w * sc1 + a2.w * sc2 + a3.w * sc3;
    *(float4*)(pb + t * 4) = v;
    if (t == 0) { pb[1024] = mb; pb[1025] = sb; }
}

// ---------------- merge chunk partials -> context (packed into cat second half) + (m,s)
__global__ void k_attn_combine(const float* __restrict__ part, float* __restrict__ cat,
                               float* __restrict__ ms)
{
    int b = blockIdx.x, t = threadIdx.x;
    float m = -INFINITY;
#pragma unroll
    for (int c = 0; c < NCHUNK; ++c)
        m = fmaxf(m, part[(size_t)(c * B + b) * PSTRIDE + 1024]);
    float s = 0.f, scl[NCHUNK];
#pragma unroll
    for (int c = 0; c < NCHUNK; ++c) {
        const float* pb = part + (size_t)(c * B + b) * PSTRIDE;
        scl[c] = expf(pb[1024] - m);
        s += pb[1025] * scl[c];
    }
    float4 v = make_float4(0.f, 0.f, 0.f, 0.f);
#pragma unroll
    for (int c = 0; c < NCHUNK; ++c) {
        float4 p = *(const float4*)(part + (size_t)(c * B + b) * PSTRIDE + t * 4);
        v.x += p.x * scl[c]; v.y += p.y * scl[c]; v.z += p.z * scl[c]; v.w += p.w * scl[c];
    }
    float inv = 1.f / s;
    v.x *= inv; v.y *= inv; v.z *= inv; v.w *= inv;
    ((float4*)cat)[(256 + t) * B + b] = v;      // k = 1024 + t*4 (context part)
    if (t == 0) { ms[b * 2] = m; ms[b * 2 + 1] = s; }
}

// ---------------- attn output normalize
__global__ void k_attn_norm(const float* __restrict__ energy, const float* __restrict__ ms,
                            float* __restrict__ attn)
{
    int idx = blockIdx.x * blockDim.x + threadIdx.x;   // [0, 131072)
    int b = idx >> 11;
    float m = ms[b * 2], s = ms[b * 2 + 1];
    attn[idx] = expf(energy[idx] - m) / s;
}

extern "C" void kernel_launch(void* const* d_in, const int* in_sizes, int n_in,
                              void* d_out, int out_size, void* d_ws, size_t ws_size,
                              hipStream_t stream)
{
    const int*   seq    = (const int*)d_in[0];
    const float* enc    = (const float*)d_in[1];
    const float* h0     = (const float*)d_in[2];
    const float* c0     = (const float*)d_in[3];
    const float* emb    = (const float*)d_in[4];
    const float* W_ih   = (const float*)d_in[5];
    const float* W_hh   = (const float*)d_in[6];
    const float* b_ih   = (const float*)d_in[7];
    const float* b_hh   = (const float*)d_in[8];
    const float* W_cat  = (const float*)d_in[9];
    const float* b_cat  = (const float*)d_in[10];
    const float* W_out  = (const float*)d_in[11];
    const float* b_out  = (const float*)d_in[12];
    float* out = (float*)d_out;
    float* ws  = (float*)d_ws;

    float* xh     = ws + WS_XH4;
    float* gatesT = ws + WS_GATES;
    float* cat    = ws + WS_CAT4;
    float* energy = ws + WS_ENERGY;
    float* part   = ws + WS_PART;
    float* ms     = ws + WS_MS;
    float* conc   = ws + WS_CONCAT;   // bf16-packed A for vocab MFMA

    k_embed<<<B, 256, 0, stream>>>(seq, emb, h0, xh);
    // gates = [x;h] @ [W_ih | W_hh]^T + b_ih + b_hh : N=4096, K=1024(+1024)
    // ROWS=4, GR=2 -> 16 rows/block, 256 blocks (1024 waves, act L2 traffic halved)
    k_sgemm<1024, true, 4, 2, 0><<<256, 256, 0, stream>>>(
        (const float4*)xh, W_ih, W_hh, b_ih, b_hh, 4 * Hd, gatesT, 0);
    k_pointwise<<<256, 256, 0, stream>>>(gatesT, c0, out + OUT_H1, out + OUT_C1, cat);
    k_attn_part<<<dim3(NCHUNK, B), 256, 0, stream>>>(enc, out + OUT_H1, energy, part);
    k_attn_combine<<<B, 256, 0, stream>>>(part, cat, ms);
    k_attn_norm<<<512, 256, 0, stream>>>(energy, ms, out + OUT_ATTN);
    // concat_out = tanh([h1;ctx] @ W_concat^T + b) : N=1024, K=2048 -> bf16 pack
    k_sgemm<2048, false, 2, 2, 1><<<128, 256, 0, stream>>>(
        (const float4*)cat, W_cat, nullptr, b_cat, nullptr, Hd, conc, 0);
    // output = concat_out @ W_out^T + b_out : N=50257 rows, K=1024, bf16 MFMA
    // 16 rows/wave, 64 rows/block -> ceil(50257/64)=786 blocks
    k_vocab_mfma<<<786, 256, 0, stream>>>(
        (const __bf16*)conc, W_out, b_out, out);
}

// Round 6
// 303.509 us; speedup vs baseline: 2.7615x; 1.2449x over previous
//
#include <hip/hip_runtime.h>
#include <math.h>

#define B 64
#define Lw 2048
#define Hd 1024
#define Vd 50257

// ws offsets (in floats)
#define WS_XHB    0          // bf16 pack [384][64][8]: x(kb 0..127), h_hi(128..255), h_lo(256..383) = 98304 f
#define WS_GATES  98304      // gatesT [4096][64] fp32 = 262144
#define WS_CATB   360448     // bf16 pack [256][64][8]: h1(kb 0..127), ctx(128..255) = 65536 f
#define WS_ENERGY 425984     // energies [64][2048] = 131072
#define WS_PART   557056     // 16*64 partials * 1032 = 1056768
#define WS_CONC   1613824    // concat_out bf16 pack [128][64][8] = 32768 f

// d_out offsets (floats): output[B][V], h1[1][B][H], c1[1][B][H], attn[B][1][L]
#define OUT_H1   3216448
#define OUT_C1   3281984
#define OUT_ATTN 3347520

#define NCHUNK 16
#define LCHUNK 128
#define PSTRIDE 1032

typedef __bf16 bf16x8 __attribute__((ext_vector_type(8)));
typedef float f32x4 __attribute__((ext_vector_type(4)));

__device__ __forceinline__ float sigm(float x) { return 1.f / (1.f + expf(-x)); }

#define CVT8(dst, w0, w1)                                            \
    dst[0] = (__bf16)w0.x; dst[1] = (__bf16)w0.y;                    \
    dst[2] = (__bf16)w0.z; dst[3] = (__bf16)w0.w;                    \
    dst[4] = (__bf16)w1.x; dst[5] = (__bf16)w1.y;                    \
    dst[6] = (__bf16)w1.z; dst[7] = (__bf16)w1.w;

// ---------------- embed + bf16 fragment pack of [x ; h_hi ; h_lo]
// layout: xhb[kb][b][8], kb = k/8; x at kb, h_hi at 128+kb, h_lo at 256+kb
__global__ void k_embed(const int* __restrict__ seq, const float* __restrict__ emb,
                        const float* __restrict__ h0, __bf16* __restrict__ xhb)
{
    int b = blockIdx.x;
    int t = threadIdx.x;               // handles k = t*4 .. t*4+3
    int tok = seq[b];
    float4 xv = *(const float4*)(emb + (size_t)tok * Hd + t * 4);
    float4 hv = *(const float4*)(h0 + (size_t)b * Hd + t * 4);
    int kb = t >> 1, ko = (t & 1) * 4;
    __bf16* xp = xhb + (size_t)kb * 512 + b * 8 + ko;
    xp[0] = (__bf16)xv.x; xp[1] = (__bf16)xv.y;
    xp[2] = (__bf16)xv.z; xp[3] = (__bf16)xv.w;
    __bf16* hp = xhb + (size_t)(128 + kb) * 512 + b * 8 + ko;
    __bf16* lp = xhb + (size_t)(256 + kb) * 512 + b * 8 + ko;
    float h[4] = {hv.x, hv.y, hv.z, hv.w};
#pragma unroll
    for (int i = 0; i < 4; ++i) {
        __bf16 hi = (__bf16)h[i];
        hp[i] = hi;
        lp[i] = (__bf16)(h[i] - (float)hi);
    }
}

// ---------------- gates = [x;h] @ [W_ih|W_hh]^T + biases, via MFMA
// x-part plain bf16 (tiny terms); h-part split hi/lo (fp32-equivalent) to
// protect h1 -> softmax. One wave: 16 gate-rows x 64 batches.
__global__ void k_gates_mfma(const __bf16* __restrict__ xhb,
                             const float* __restrict__ W_ih, const float* __restrict__ W_hh,
                             const float* __restrict__ b_ih, const float* __restrict__ b_hh,
                             float* __restrict__ gatesT)
{
    int wave = threadIdx.x >> 6, lane = threadIdx.x & 63;
    int n0 = (blockIdx.x * 4 + wave) * 16;     // 64 blocks -> n0 in [0,4096)
    int nl = n0 + (lane & 15);
    int kq = lane >> 4;
    const float* wp1 = W_ih + (size_t)nl * Hd + kq * 8;
    const float* wp2 = W_hh + (size_t)nl * Hd + kq * 8;
    const __bf16* ap = xhb + (lane & 15) * 8;

    f32x4 acc[4] = {{0.f,0.f,0.f,0.f},{0.f,0.f,0.f,0.f},
                    {0.f,0.f,0.f,0.f},{0.f,0.f,0.f,0.f}};

#pragma unroll 4
    for (int k0 = 0; k0 < Hd; k0 += 32) {      // x-part, plain bf16
        float4 w0 = *(const float4*)(wp1 + k0);
        float4 w1 = *(const float4*)(wp1 + k0 + 4);
        bf16x8 bf; CVT8(bf, w0, w1);
        int kb = (k0 >> 3) + kq;
#pragma unroll
        for (int mt = 0; mt < 4; ++mt) {
            bf16x8 a = *(const bf16x8*)(ap + (size_t)kb * 512 + mt * 128);
            acc[mt] = __builtin_amdgcn_mfma_f32_16x16x32_bf16(a, bf, acc[mt], 0, 0, 0);
        }
    }
#pragma unroll 2
    for (int k0 = 0; k0 < Hd; k0 += 32) {      // h-part, split hi/lo
        float4 w0 = *(const float4*)(wp2 + k0);
        float4 w1 = *(const float4*)(wp2 + k0 + 4);
        bf16x8 bhi, blo;
        float wf[8] = {w0.x, w0.y, w0.z, w0.w, w1.x, w1.y, w1.z, w1.w};
#pragma unroll
        for (int i = 0; i < 8; ++i) {
            __bf16 hi = (__bf16)wf[i];
            bhi[i] = hi;
            blo[i] = (__bf16)(wf[i] - (float)hi);
        }
        int kb = (k0 >> 3) + kq;
#pragma unroll
        for (int mt = 0; mt < 4; ++mt) {
            bf16x8 ahi = *(const bf16x8*)(ap + (size_t)(128 + kb) * 512 + mt * 128);
            bf16x8 alo = *(const bf16x8*)(ap + (size_t)(256 + kb) * 512 + mt * 128);
            acc[mt] = __builtin_amdgcn_mfma_f32_16x16x32_bf16(ahi, bhi, acc[mt], 0, 0, 0);
            acc[mt] = __builtin_amdgcn_mfma_f32_16x16x32_bf16(ahi, blo, acc[mt], 0, 0, 0);
            acc[mt] = __builtin_amdgcn_mfma_f32_16x16x32_bf16(alo, bhi, acc[mt], 0, 0, 0);
        }
    }

    float bv = b_ih[nl] + b_hh[nl];
#pragma unroll
    for (int mt = 0; mt < 4; ++mt)
#pragma unroll
        for (int r = 0; r < 4; ++r) {
            int m = mt * 16 + (lane >> 4) * 4 + r;       // batch
            gatesT[(size_t)nl * B + m] = acc[mt][r] + bv;
        }
}

// ---------------- LSTM pointwise (PyTorch gate order i,f,g,o)
__global__ void k_pointwise(const float* __restrict__ gatesT, const float* __restrict__ c0,
                            float* __restrict__ h1o, float* __restrict__ c1o,
                            __bf16* __restrict__ catb)
{
    int wave = threadIdx.x >> 6, lane = threadIdx.x & 63;
    int hh = blockIdx.x * 4 + wave;
    float gi = gatesT[(size_t)(0 * Hd + hh) * B + lane];
    float gf = gatesT[(size_t)(1 * Hd + hh) * B + lane];
    float gg = gatesT[(size_t)(2 * Hd + hh) * B + lane];
    float go = gatesT[(size_t)(3 * Hd + hh) * B + lane];
    float c  = c0[(size_t)lane * Hd + hh];
    float c1 = sigm(gf) * c + sigm(gi) * tanhf(gg);
    float h1 = sigm(go) * tanhf(c1);
    h1o[(size_t)lane * Hd + hh] = h1;
    c1o[(size_t)lane * Hd + hh] = c1;
    catb[(size_t)(hh >> 3) * 512 + lane * 8 + (hh & 7)] = (__bf16)h1;   // A-frag pack
}

// ---------------- fused energies + online-softmax context partials (one enc pass)
__global__ void k_attn_part(const float* __restrict__ enc, const float* __restrict__ h1,
                            float* __restrict__ energy, float* __restrict__ part)
{
    int chunk = blockIdx.x, b = blockIdx.y;
    int wave = threadIdx.x >> 6, lane = threadIdx.x & 63;

    float4 qv[4], ctx[4];
#pragma unroll
    for (int q = 0; q < 4; ++q) {
        qv[q] = *(const float4*)(h1 + (size_t)b * Hd + q * 256 + lane * 4);
        ctx[q] = make_float4(0.f, 0.f, 0.f, 0.f);
    }
    float m = -INFINITY, s = 0.f;

    for (int i = 0; i < LCHUNK / 4; ++i) {
        int l = chunk * LCHUNK + i * 4 + wave;
        const float* ep = enc + ((size_t)l * B + b) * Hd;
        float4 ev[4];
#pragma unroll
        for (int q = 0; q < 4; ++q) ev[q] = *(const float4*)(ep + q * 256 + lane * 4);
        float d = 0.f;
#pragma unroll
        for (int q = 0; q < 4; ++q)
            d += ev[q].x * qv[q].x + ev[q].y * qv[q].y + ev[q].z * qv[q].z + ev[q].w * qv[q].w;
#pragma unroll
        for (int off = 32; off >= 1; off >>= 1) d += __shfl_xor(d, off);
        if (lane == 0) energy[(size_t)b * Lw + l] = d;

        if (d > m) {                       // wave-uniform branch
            float sc = expf(m - d);
            s *= sc;
#pragma unroll
            for (int q = 0; q < 4; ++q) {
                ctx[q].x *= sc; ctx[q].y *= sc; ctx[q].z *= sc; ctx[q].w *= sc;
            }
            m = d;
        }
        float w = expf(d - m);
        s += w;
#pragma unroll
        for (int q = 0; q < 4; ++q) {
            ctx[q].x += w * ev[q].x; ctx[q].y += w * ev[q].y;
            ctx[q].z += w * ev[q].z; ctx[q].w += w * ev[q].w;
        }
    }

    // combine the 4 waves of this block
    __shared__ float lctx[4][Hd];
    __shared__ float lms[4][2];
#pragma unroll
    for (int q = 0; q < 4; ++q)
        *(float4*)(&lctx[wave][q * 256 + lane * 4]) = ctx[q];
    if (lane == 0) { lms[wave][0] = m; lms[wave][1] = s; }
    __syncthreads();

    float mb = fmaxf(fmaxf(lms[0][0], lms[1][0]), fmaxf(lms[2][0], lms[3][0]));
    float sc0 = expf(lms[0][0] - mb), sc1 = expf(lms[1][0] - mb);
    float sc2 = expf(lms[2][0] - mb), sc3 = expf(lms[3][0] - mb);
    float sb = lms[0][1] * sc0 + lms[1][1] * sc1 + lms[2][1] * sc2 + lms[3][1] * sc3;

    int t = threadIdx.x;
    float* pb = part + (size_t)(chunk * B + b) * PSTRIDE;
    float4 a0 = *(float4*)(&lctx[0][t * 4]);
    float4 a1 = *(float4*)(&lctx[1][t * 4]);
    float4 a2 = *(float4*)(&lctx[2][t * 4]);
    float4 a3 = *(float4*)(&lctx[3][t * 4]);
    float4 v;
    v.x = a0.x * sc0 + a1.x * sc1 + a2.x * sc2 + a3.x * sc3;
    v.y = a0.y * sc0 + a1.y * sc1 + a2.y * sc2 + a3.y * sc3;
    v.z = a0.z * sc0 + a1.z * sc1 + a2.z * sc2 + a3.z * sc3;
    v.w = a0.w * sc0 + a1.w * sc1 + a2.w * sc2 + a3.w * sc3;
    *(float4*)(pb + t * 4) = v;
    if (t == 0) { pb[1024] = mb; pb[1025] = sb; }
}

// ---------------- merge partials -> ctx (bf16 pack) + attn output normalize
__global__ void k_attn_combine(const float* __restrict__ part,
                               const float* __restrict__ energy,
                               __bf16* __restrict__ catb, float* __restrict__ attn)
{
    int b = blockIdx.x, t = threadIdx.x;
    float m = -INFINITY;
#pragma unroll
    for (int c = 0; c < NCHUNK; ++c)
        m = fmaxf(m, part[(size_t)(c * B + b) * PSTRIDE + 1024]);
    float s = 0.f, scl[NCHUNK];
#pragma unroll
    for (int c = 0; c < NCHUNK; ++c) {
        const float* pb = part + (size_t)(c * B + b) * PSTRIDE;
        scl[c] = expf(pb[1024] - m);
        s += pb[1025] * scl[c];
    }
    float4 v = make_float4(0.f, 0.f, 0.f, 0.f);
#pragma unroll
    for (int c = 0; c < NCHUNK; ++c) {
        float4 p = *(const float4*)(part + (size_t)(c * B + b) * PSTRIDE + t * 4);
        v.x += p.x * scl[c]; v.y += p.y * scl[c]; v.z += p.z * scl[c]; v.w += p.w * scl[c];
    }
    float inv = 1.f / s;
    v.x *= inv; v.y *= inv; v.z *= inv; v.w *= inv;
    int k = 1024 + t * 4;                                   // ctx k index
    __bf16* cp = catb + (size_t)(k >> 3) * 512 + b * 8 + (k & 7);
    cp[0] = (__bf16)v.x; cp[1] = (__bf16)v.y;
    cp[2] = (__bf16)v.z; cp[3] = (__bf16)v.w;

    // fused attn normalize: 8 energies per thread
#pragma unroll
    for (int j = 0; j < 8; ++j) {
        int l = t + j * 256;
        attn[(size_t)b * Lw + l] = expf(energy[(size_t)b * Lw + l] - m) * inv;
    }
}

// ---------------- concat_out = tanh([h1;ctx] @ W_concat^T + b), via bf16 MFMA
// output packed as bf16 A-fragments [n/8][64][8] for the vocab GEMM
__global__ void k_concat_mfma(const __bf16* __restrict__ catb,
                              const float* __restrict__ W, const float* __restrict__ bias,
                              __bf16* __restrict__ conc)
{
    int wave = threadIdx.x >> 6, lane = threadIdx.x & 63;
    int n0 = (blockIdx.x * 4 + wave) * 16;     // 16 blocks -> n0 in [0,1024)
    int nl = n0 + (lane & 15);
    int kq = lane >> 4;
    const float* wp = W + (size_t)nl * (2 * Hd) + kq * 8;
    const __bf16* ap = catb + (lane & 15) * 8;

    f32x4 acc[4] = {{0.f,0.f,0.f,0.f},{0.f,0.f,0.f,0.f},
                    {0.f,0.f,0.f,0.f},{0.f,0.f,0.f,0.f}};

#pragma unroll 4
    for (int k0 = 0; k0 < 2 * Hd; k0 += 32) {
        float4 w0 = *(const float4*)(wp + k0);
        float4 w1 = *(const float4*)(wp + k0 + 4);
        bf16x8 bf; CVT8(bf, w0, w1);
        int kb = (k0 >> 3) + kq;
#pragma unroll
        for (int mt = 0; mt < 4; ++mt) {
            bf16x8 a = *(const bf16x8*)(ap + (size_t)kb * 512 + mt * 128);
            acc[mt] = __builtin_amdgcn_mfma_f32_16x16x32_bf16(a, bf, acc[mt], 0, 0, 0);
        }
    }

    float bv = bias[nl];
#pragma unroll
    for (int mt = 0; mt < 4; ++mt)
#pragma unroll
        for (int r = 0; r < 4; ++r) {
            int m = mt * 16 + (lane >> 4) * 4 + r;       // batch
            float val = tanhf(acc[mt][r] + bv);
            conc[(size_t)(nl >> 3) * 512 + m * 8 + (nl & 7)] = (__bf16)val;
        }
}

// ---------------- vocab projection via bf16 MFMA 16x16x32 (unchanged from r5)
__global__ void k_vocab_mfma(const __bf16* __restrict__ apack,
                             const float* __restrict__ W,
                             const float* __restrict__ bias,
                             float* __restrict__ out)
{
    int wave = threadIdx.x >> 6;
    int lane = threadIdx.x & 63;
    int n0 = (blockIdx.x * 4 + wave) * 16;
    if (n0 > Vd - 16) n0 = Vd - 16;        // tail shift-down (dup writes benign)

    int nl = n0 + (lane & 15);
    int kq = lane >> 4;
    const float* wp = W + (size_t)nl * Hd + kq * 8;
    const __bf16* ap = apack + (size_t)(lane & 15) * 8;

    f32x4 acc[4] = {{0.f,0.f,0.f,0.f},{0.f,0.f,0.f,0.f},
                    {0.f,0.f,0.f,0.f},{0.f,0.f,0.f,0.f}};

#pragma unroll 4
    for (int k0 = 0; k0 < Hd; k0 += 32) {
        float4 w0 = *(const float4*)(wp + k0);
        float4 w1 = *(const float4*)(wp + k0 + 4);
        bf16x8 bf; CVT8(bf, w0, w1);
        int kb = (k0 >> 3) + kq;
#pragma unroll
        for (int mt = 0; mt < 4; ++mt) {
            bf16x8 afrag = *(const bf16x8*)(ap + (size_t)kb * 512 + mt * 128);
            acc[mt] = __builtin_amdgcn_mfma_f32_16x16x32_bf16(afrag, bf, acc[mt], 0, 0, 0);
        }
    }

    float bv = bias[nl];
#pragma unroll
    for (int mt = 0; mt < 4; ++mt)
#pragma unroll
        for (int r = 0; r < 4; ++r) {
            int m = mt * 16 + (lane >> 4) * 4 + r;   // batch (C/D row)
            out[(size_t)m * Vd + nl] = acc[mt][r] + bv;
        }
}

extern "C" void kernel_launch(void* const* d_in, const int* in_sizes, int n_in,
                              void* d_out, int out_size, void* d_ws, size_t ws_size,
                              hipStream_t stream)
{
    const int*   seq    = (const int*)d_in[0];
    const float* enc    = (const float*)d_in[1];
    const float* h0     = (const float*)d_in[2];
    const float* c0     = (const float*)d_in[3];
    const float* emb    = (const float*)d_in[4];
    const float* W_ih   = (const float*)d_in[5];
    const float* W_hh   = (const float*)d_in[6];
    const float* b_ih   = (const float*)d_in[7];
    const float* b_hh   = (const float*)d_in[8];
    const float* W_cat  = (const float*)d_in[9];
    const float* b_cat  = (const float*)d_in[10];
    const float* W_out  = (const float*)d_in[11];
    const float* b_out  = (const float*)d_in[12];
    float* out = (float*)d_out;
    float* ws  = (float*)d_ws;

    __bf16* xhb   = (__bf16*)(ws + WS_XHB);
    float*  gatesT = ws + WS_GATES;
    __bf16* catb  = (__bf16*)(ws + WS_CATB);
    float*  energy = ws + WS_ENERGY;
    float*  part   = ws + WS_PART;
    __bf16* conc  = (__bf16*)(ws + WS_CONC);

    k_embed<<<B, 256, 0, stream>>>(seq, emb, h0, xhb);
    // gates: N=4096 rows, 16/wave, 64 rows/block -> 64 blocks
    k_gates_mfma<<<64, 256, 0, stream>>>(xhb, W_ih, W_hh, b_ih, b_hh, gatesT);
    k_pointwise<<<256, 256, 0, stream>>>(gatesT, c0, out + OUT_H1, out + OUT_C1, catb);
    k_attn_part<<<dim3(NCHUNK, B), 256, 0, stream>>>(enc, out + OUT_H1, energy, part);
    k_attn_combine<<<B, 256, 0, stream>>>(part, energy, catb, out + OUT_ATTN);
    // concat: N=1024 rows -> 16 blocks
    k_concat_mfma<<<16, 256, 0, stream>>>(catb, W_cat, b_cat, conc);
    // vocab: N=50257 rows -> 786 blocks
    k_vocab_mfma<<<786, 256, 0, stream>>>(conc, W_out, b_out, out);
}

// Round 7
// 232.231 us; speedup vs baseline: 3.6090x; 1.3069x over previous
//
#include <hip/hip_runtime.h>
#include <math.h>

#define B 64
#define Lw 2048
#define Hd 1024
#define Vd 50257

// ws offsets (in floats)
#define WS_XHB    0          // bf16 pack [384][64][8]: x(kb 0..127), h_hi(128..255), h_lo(256..383)
#define WS_GATES  98304      // gatesT [4096][64] fp32 = 262144
#define WS_CATB   360448     // bf16 pack [256][64][8]: h1(kb 0..127), ctx(128..255)
#define WS_ENERGY 425984     // energies [64][2048] = 131072
#define WS_PART   557056     // 32*64 partials * 1032 = 2113536
#define WS_CONC   2670592    // concat_out bf16 pack [128][64][8] = 32768 f

// d_out offsets (floats): output[B][V], h1[1][B][H], c1[1][B][H], attn[B][1][L]
#define OUT_H1   3216448
#define OUT_C1   3281984
#define OUT_ATTN 3347520

#define NCHUNK 32
#define LCHUNK 64
#define PSTRIDE 1032

typedef __bf16 bf16x8 __attribute__((ext_vector_type(8)));
typedef float f32x4 __attribute__((ext_vector_type(4)));

__device__ __forceinline__ float sigm(float x) { return 1.f / (1.f + expf(-x)); }

#define CVT8(dst, w0, w1)                                            \
    dst[0] = (__bf16)w0.x; dst[1] = (__bf16)w0.y;                    \
    dst[2] = (__bf16)w0.z; dst[3] = (__bf16)w0.w;                    \
    dst[4] = (__bf16)w1.x; dst[5] = (__bf16)w1.y;                    \
    dst[6] = (__bf16)w1.z; dst[7] = (__bf16)w1.w;

// ---------------- embed + bf16 fragment pack of [x ; h_hi ; h_lo]
__global__ void k_embed(const int* __restrict__ seq, const float* __restrict__ emb,
                        const float* __restrict__ h0, __bf16* __restrict__ xhb)
{
    int b = blockIdx.x;
    int t = threadIdx.x;               // handles k = t*4 .. t*4+3
    int tok = seq[b];
    float4 xv = *(const float4*)(emb + (size_t)tok * Hd + t * 4);
    float4 hv = *(const float4*)(h0 + (size_t)b * Hd + t * 4);
    int kb = t >> 1, ko = (t & 1) * 4;
    __bf16* xp = xhb + (size_t)kb * 512 + b * 8 + ko;
    xp[0] = (__bf16)xv.x; xp[1] = (__bf16)xv.y;
    xp[2] = (__bf16)xv.z; xp[3] = (__bf16)xv.w;
    __bf16* hp = xhb + (size_t)(128 + kb) * 512 + b * 8 + ko;
    __bf16* lp = xhb + (size_t)(256 + kb) * 512 + b * 8 + ko;
    float h[4] = {hv.x, hv.y, hv.z, hv.w};
#pragma unroll
    for (int i = 0; i < 4; ++i) {
        __bf16 hi = (__bf16)h[i];
        hp[i] = hi;
        lp[i] = (__bf16)(h[i] - (float)hi);
    }
}

// ---------------- gates via MFMA, K-split over 8 waves (LDS reduce)
// waves 0-3: x-part (plain bf16), k-window 256 each; waves 4-7: h-part (hi/lo).
__global__ void k_gates_mfma(const __bf16* __restrict__ xhb,
                             const float* __restrict__ W_ih, const float* __restrict__ W_hh,
                             const float* __restrict__ b_ih, const float* __restrict__ b_hh,
                             float* __restrict__ gatesT)
{
    __shared__ float lds[8][64][20];
    int wave = threadIdx.x >> 6, lane = threadIdx.x & 63;
    int n0 = blockIdx.x * 16;
    int nl = n0 + (lane & 15);
    int kq = lane >> 4;
    int isH = wave >> 2;
    int kbase = (wave & 3) * 256;

    const float* wp = (isH ? W_hh : W_ih) + (size_t)nl * Hd + kbase + kq * 8;
    const __bf16* apx = xhb + (lane & 15) * 8;

    f32x4 acc[4] = {{0.f,0.f,0.f,0.f},{0.f,0.f,0.f,0.f},
                    {0.f,0.f,0.f,0.f},{0.f,0.f,0.f,0.f}};

    if (!isH) {
#pragma unroll 4
        for (int k0 = 0; k0 < 256; k0 += 32) {
            float4 w0 = *(const float4*)(wp + k0);
            float4 w1 = *(const float4*)(wp + k0 + 4);
            bf16x8 bf; CVT8(bf, w0, w1);
            int kb = ((kbase + k0) >> 3) + kq;
#pragma unroll
            for (int mt = 0; mt < 4; ++mt) {
                bf16x8 a = *(const bf16x8*)(apx + (size_t)kb * 512 + mt * 128);
                acc[mt] = __builtin_amdgcn_mfma_f32_16x16x32_bf16(a, bf, acc[mt], 0, 0, 0);
            }
        }
    } else {
#pragma unroll 2
        for (int k0 = 0; k0 < 256; k0 += 32) {
            float4 w0 = *(const float4*)(wp + k0);
            float4 w1 = *(const float4*)(wp + k0 + 4);
            bf16x8 bhi, blo;
            float wf[8] = {w0.x, w0.y, w0.z, w0.w, w1.x, w1.y, w1.z, w1.w};
#pragma unroll
            for (int i = 0; i < 8; ++i) {
                __bf16 hi = (__bf16)wf[i];
                bhi[i] = hi;
                blo[i] = (__bf16)(wf[i] - (float)hi);
            }
            int kb = ((kbase + k0) >> 3) + kq;
#pragma unroll
            for (int mt = 0; mt < 4; ++mt) {
                bf16x8 ahi = *(const bf16x8*)(apx + (size_t)(128 + kb) * 512 + mt * 128);
                bf16x8 alo = *(const bf16x8*)(apx + (size_t)(256 + kb) * 512 + mt * 128);
                acc[mt] = __builtin_amdgcn_mfma_f32_16x16x32_bf16(ahi, bhi, acc[mt], 0, 0, 0);
                acc[mt] = __builtin_amdgcn_mfma_f32_16x16x32_bf16(ahi, blo, acc[mt], 0, 0, 0);
                acc[mt] = __builtin_amdgcn_mfma_f32_16x16x32_bf16(alo, bhi, acc[mt], 0, 0, 0);
            }
        }
    }

#pragma unroll
    for (int mt = 0; mt < 4; ++mt)
        *(f32x4*)&lds[wave][lane][mt * 4] = acc[mt];
    __syncthreads();

    if (wave < 4) {
        int mt = wave;
        float bv = b_ih[nl] + b_hh[nl];
#pragma unroll
        for (int r = 0; r < 4; ++r) {
            float s = 0.f;
#pragma unroll
            for (int w = 0; w < 8; ++w) s += lds[w][lane][mt * 4 + r];
            int m = mt * 16 + kq * 4 + r;       // batch
            gatesT[(size_t)nl * B + m] = s + bv;
        }
    }
}

// ---------------- LSTM pointwise (PyTorch gate order i,f,g,o)
__global__ void k_pointwise(const float* __restrict__ gatesT, const float* __restrict__ c0,
                            float* __restrict__ h1o, float* __restrict__ c1o,
                            __bf16* __restrict__ catb)
{
    int wave = threadIdx.x >> 6, lane = threadIdx.x & 63;
    int hh = blockIdx.x * 4 + wave;
    float gi = gatesT[(size_t)(0 * Hd + hh) * B + lane];
    float gf = gatesT[(size_t)(1 * Hd + hh) * B + lane];
    float gg = gatesT[(size_t)(2 * Hd + hh) * B + lane];
    float go = gatesT[(size_t)(3 * Hd + hh) * B + lane];
    float c  = c0[(size_t)lane * Hd + hh];
    float c1 = sigm(gf) * c + sigm(gi) * tanhf(gg);
    float h1 = sigm(go) * tanhf(c1);
    h1o[(size_t)lane * Hd + hh] = h1;
    c1o[(size_t)lane * Hd + hh] = c1;
    catb[(size_t)(hh >> 3) * 512 + lane * 8 + (hh & 7)] = (__bf16)h1;   // A-frag pack
}

// ---------------- fused energies + online-softmax context partials (one enc pass)
__global__ void k_attn_part(const float* __restrict__ enc, const float* __restrict__ h1,
                            float* __restrict__ energy, float* __restrict__ part)
{
    int chunk = blockIdx.x, b = blockIdx.y;
    int wave = threadIdx.x >> 6, lane = threadIdx.x & 63;

    float4 qv[4], ctx[4];
#pragma unroll
    for (int q = 0; q < 4; ++q) {
        qv[q] = *(const float4*)(h1 + (size_t)b * Hd + q * 256 + lane * 4);
        ctx[q] = make_float4(0.f, 0.f, 0.f, 0.f);
    }
    float m = -INFINITY, s = 0.f;

    for (int i = 0; i < LCHUNK / 4; ++i) {
        int l = chunk * LCHUNK + i * 4 + wave;
        const float* ep = enc + ((size_t)l * B + b) * Hd;
        float4 ev[4];
#pragma unroll
        for (int q = 0; q < 4; ++q) ev[q] = *(const float4*)(ep + q * 256 + lane * 4);
        float d = 0.f;
#pragma unroll
        for (int q = 0; q < 4; ++q)
            d += ev[q].x * qv[q].x + ev[q].y * qv[q].y + ev[q].z * qv[q].z + ev[q].w * qv[q].w;
#pragma unroll
        for (int off = 32; off >= 1; off >>= 1) d += __shfl_xor(d, off);
        if (lane == 0) energy[(size_t)b * Lw + l] = d;

        if (d > m) {                       // wave-uniform branch
            float sc = expf(m - d);
            s *= sc;
#pragma unroll
            for (int q = 0; q < 4; ++q) {
                ctx[q].x *= sc; ctx[q].y *= sc; ctx[q].z *= sc; ctx[q].w *= sc;
            }
            m = d;
        }
        float w = expf(d - m);
        s += w;
#pragma unroll
        for (int q = 0; q < 4; ++q) {
            ctx[q].x += w * ev[q].x; ctx[q].y += w * ev[q].y;
            ctx[q].z += w * ev[q].z; ctx[q].w += w * ev[q].w;
        }
    }

    // combine the 4 waves of this block
    __shared__ float lctx[4][Hd];
    __shared__ float lms[4][2];
#pragma unroll
    for (int q = 0; q < 4; ++q)
        *(float4*)(&lctx[wave][q * 256 + lane * 4]) = ctx[q];
    if (lane == 0) { lms[wave][0] = m; lms[wave][1] = s; }
    __syncthreads();

    float mb = fmaxf(fmaxf(lms[0][0], lms[1][0]), fmaxf(lms[2][0], lms[3][0]));
    float sc0 = expf(lms[0][0] - mb), sc1 = expf(lms[1][0] - mb);
    float sc2 = expf(lms[2][0] - mb), sc3 = expf(lms[3][0] - mb);
    float sb = lms[0][1] * sc0 + lms[1][1] * sc1 + lms[2][1] * sc2 + lms[3][1] * sc3;

    int t = threadIdx.x;
    float* pb = part + (size_t)(chunk * B + b) * PSTRIDE;
    float4 a0 = *(float4*)(&lctx[0][t * 4]);
    float4 a1 = *(float4*)(&lctx[1][t * 4]);
    float4 a2 = *(float4*)(&lctx[2][t * 4]);
    float4 a3 = *(float4*)(&lctx[3][t * 4]);
    float4 v;
    v.x = a0.x * sc0 + a1.x * sc1 + a2.x * sc2 + a3.x * sc3;
    v.y = a0.y * sc0 + a1.y * sc1 + a2.y * sc2 + a3.y * sc3;
    v.z = a0.z * sc0 + a1.z * sc1 + a2.z * sc2 + a3.z * sc3;
    v.w = a0.w * sc0 + a1.w * sc1 + a2.w * sc2 + a3.w * sc3;
    *(float4*)(pb + t * 4) = v;
    if (t == 0) { pb[1024] = mb; pb[1025] = sb; }
}

// ---------------- merge partials -> ctx (bf16 pack) + attn output normalize
__global__ void k_attn_combine(const float* __restrict__ part,
                               const float* __restrict__ energy,
                               __bf16* __restrict__ catb, float* __restrict__ attn)
{
    int b = blockIdx.x, t = threadIdx.x;
    float m = -INFINITY;
#pragma unroll
    for (int c = 0; c < NCHUNK; ++c)
        m = fmaxf(m, part[(size_t)(c * B + b) * PSTRIDE + 1024]);
    float s = 0.f, scl[NCHUNK];
#pragma unroll
    for (int c = 0; c < NCHUNK; ++c) {
        const float* pb = part + (size_t)(c * B + b) * PSTRIDE;
        scl[c] = expf(pb[1024] - m);
        s += pb[1025] * scl[c];
    }
    float4 v = make_float4(0.f, 0.f, 0.f, 0.f);
#pragma unroll
    for (int c = 0; c < NCHUNK; ++c) {
        float4 p = *(const float4*)(part + (size_t)(c * B + b) * PSTRIDE + t * 4);
        v.x += p.x * scl[c]; v.y += p.y * scl[c]; v.z += p.z * scl[c]; v.w += p.w * scl[c];
    }
    float inv = 1.f / s;
    v.x *= inv; v.y *= inv; v.z *= inv; v.w *= inv;
    int k = 1024 + t * 4;                                   // ctx k index
    __bf16* cp = catb + (size_t)(k >> 3) * 512 + b * 8 + (k & 7);
    cp[0] = (__bf16)v.x; cp[1] = (__bf16)v.y;
    cp[2] = (__bf16)v.z; cp[3] = (__bf16)v.w;

#pragma unroll
    for (int j = 0; j < 8; ++j) {
        int l = t + j * 256;
        attn[(size_t)b * Lw + l] = expf(energy[(size_t)b * Lw + l] - m) * inv;
    }
}

// ---------------- concat_out via bf16 MFMA, K-split over 8 waves (LDS reduce)
__global__ void k_concat_mfma(const __bf16* __restrict__ catb,
                              const float* __restrict__ W, const float* __restrict__ bias,
                              __bf16* __restrict__ conc)
{
    __shared__ float lds[8][64][20];
    int wave = threadIdx.x >> 6, lane = threadIdx.x & 63;
    int n0 = blockIdx.x * 16;
    int nl = n0 + (lane & 15);
    int kq = lane >> 4;
    int kbase = wave * 256;            // 8 waves x 256 = K=2048

    const float* wp = W + (size_t)nl * (2 * Hd) + kbase + kq * 8;
    const __bf16* ap = catb + (lane & 15) * 8;

    f32x4 acc[4] = {{0.f,0.f,0.f,0.f},{0.f,0.f,0.f,0.f},
                    {0.f,0.f,0.f,0.f},{0.f,0.f,0.f,0.f}};

#pragma unroll 4
    for (int k0 = 0; k0 < 256; k0 += 32) {
        float4 w0 = *(const float4*)(wp + k0);
        float4 w1 = *(const float4*)(wp + k0 + 4);
        bf16x8 bf; CVT8(bf, w0, w1);
        int kb = ((kbase + k0) >> 3) + kq;
#pragma unroll
        for (int mt = 0; mt < 4; ++mt) {
            bf16x8 a = *(const bf16x8*)(ap + (size_t)kb * 512 + mt * 128);
            acc[mt] = __builtin_amdgcn_mfma_f32_16x16x32_bf16(a, bf, acc[mt], 0, 0, 0);
        }
    }

#pragma unroll
    for (int mt = 0; mt < 4; ++mt)
        *(f32x4*)&lds[wave][lane][mt * 4] = acc[mt];
    __syncthreads();

    if (wave < 4) {
        int mt = wave;
        float bv = bias[nl];
#pragma unroll
        for (int r = 0; r < 4; ++r) {
            float s = 0.f;
#pragma unroll
            for (int w = 0; w < 8; ++w) s += lds[w][lane][mt * 4 + r];
            int m = mt * 16 + kq * 4 + r;       // batch
            conc[(size_t)(nl >> 3) * 512 + m * 8 + (nl & 7)] = (__bf16)tanhf(s + bv);
        }
    }
}

// ---------------- vocab projection via bf16 MFMA 16x16x32
__global__ void k_vocab_mfma(const __bf16* __restrict__ apack,
                             const float* __restrict__ W,
                             const float* __restrict__ bias,
                             float* __restrict__ out)
{
    int wave = threadIdx.x >> 6;
    int lane = threadIdx.x & 63;
    int n0 = (blockIdx.x * 4 + wave) * 16;
    if (n0 > Vd - 16) n0 = Vd - 16;        // tail shift-down (dup writes benign)

    int nl = n0 + (lane & 15);
    int kq = lane >> 4;
    const float* wp = W + (size_t)nl * Hd + kq * 8;
    const __bf16* ap = apack + (size_t)(lane & 15) * 8;

    f32x4 acc[4] = {{0.f,0.f,0.f,0.f},{0.f,0.f,0.f,0.f},
                    {0.f,0.f,0.f,0.f},{0.f,0.f,0.f,0.f}};

#pragma unroll 4
    for (int k0 = 0; k0 < Hd; k0 += 32) {
        float4 w0 = *(const float4*)(wp + k0);
        float4 w1 = *(const float4*)(wp + k0 + 4);
        bf16x8 bf; CVT8(bf, w0, w1);
        int kb = (k0 >> 3) + kq;
#pragma unroll
        for (int mt = 0; mt < 4; ++mt) {
            bf16x8 afrag = *(const bf16x8*)(ap + (size_t)kb * 512 + mt * 128);
            acc[mt] = __builtin_amdgcn_mfma_f32_16x16x32_bf16(afrag, bf, acc[mt], 0, 0, 0);
        }
    }

    float bv = bias[nl];
#pragma unroll
    for (int mt = 0; mt < 4; ++mt)
#pragma unroll
        for (int r = 0; r < 4; ++r) {
            int m = mt * 16 + (lane >> 4) * 4 + r;   // batch (C/D row)
            out[(size_t)m * Vd + nl] = acc[mt][r] + bv;
        }
}

extern "C" void kernel_launch(void* const* d_in, const int* in_sizes, int n_in,
                              void* d_out, int out_size, void* d_ws, size_t ws_size,
                              hipStream_t stream)
{
    const int*   seq    = (const int*)d_in[0];
    const float* enc    = (const float*)d_in[1];
    const float* h0     = (const float*)d_in[2];
    const float* c0     = (const float*)d_in[3];
    const float* emb    = (const float*)d_in[4];
    const float* W_ih   = (const float*)d_in[5];
    const float* W_hh   = (const float*)d_in[6];
    const float* b_ih   = (const float*)d_in[7];
    const float* b_hh   = (const float*)d_in[8];
    const float* W_cat  = (const float*)d_in[9];
    const float* b_cat  = (const float*)d_in[10];
    const float* W_out  = (const float*)d_in[11];
    const float* b_out  = (const float*)d_in[12];
    float* out = (float*)d_out;
    float* ws  = (float*)d_ws;

    __bf16* xhb    = (__bf16*)(ws + WS_XHB);
    float*  gatesT = ws + WS_GATES;
    __bf16* catb   = (__bf16*)(ws + WS_CATB);
    float*  energy = ws + WS_ENERGY;
    float*  part   = ws + WS_PART;
    __bf16* conc   = (__bf16*)(ws + WS_CONC);

    k_embed<<<B, 256, 0, stream>>>(seq, emb, h0, xhb);
    // gates: 256 blocks x 512 threads (8-way K-split per 16-row tile)
    k_gates_mfma<<<256, 512, 0, stream>>>(xhb, W_ih, W_hh, b_ih, b_hh, gatesT);
    k_pointwise<<<256, 256, 0, stream>>>(gatesT, c0, out + OUT_H1, out + OUT_C1, catb);
    k_attn_part<<<dim3(NCHUNK, B), 256, 0, stream>>>(enc, out + OUT_H1, energy, part);
    k_attn_combine<<<B, 256, 0, stream>>>(part, energy, catb, out + OUT_ATTN);
    // concat: 64 blocks x 512 threads (8-way K-split)
    k_concat_mfma<<<64, 512, 0, stream>>>(catb, W_cat, b_cat, conc);
    // vocab: N=50257 rows -> 786 blocks
    k_vocab_mfma<<<786, 256, 0, stream>>>(conc, W_out, b_out, out);
}

// Round 8
// 228.497 us; speedup vs baseline: 3.6680x; 1.0163x over previous
//
#include <hip/hip_runtime.h>
#include <math.h>

#define B 64
#define Lw 2048
#define Hd 1024
#define Vd 50257

// ws offsets (in floats)
#define WS_XHB    0          // bf16 pack [384][64][8]: x(kb 0..127), h_hi(128..255), h_lo(256..383)
#define WS_CATB   98304      // bf16 pack [256][64][8]: h1(kb 0..127), ctx(128..255)
#define WS_ENERGY 163840     // energies [64][2048] = 131072
#define WS_PART   294912     // 32*64 partials * 1032 = 2113536
#define WS_CONC   2408448    // concat_out bf16 pack [128][64][8] = 32768 f

// d_out offsets (floats): output[B][V], h1[1][B][H], c1[1][B][H], attn[B][1][L]
#define OUT_H1   3216448
#define OUT_C1   3281984
#define OUT_ATTN 3347520

#define NCHUNK 32
#define LCHUNK 64
#define PSTRIDE 1032

typedef __bf16 bf16x8 __attribute__((ext_vector_type(8)));
typedef float f32x4 __attribute__((ext_vector_type(4)));

__device__ __forceinline__ float sigm(float x) { return 1.f / (1.f + expf(-x)); }

#define CVT8(dst, w0, w1)                                            \
    dst[0] = (__bf16)w0.x; dst[1] = (__bf16)w0.y;                    \
    dst[2] = (__bf16)w0.z; dst[3] = (__bf16)w0.w;                    \
    dst[4] = (__bf16)w1.x; dst[5] = (__bf16)w1.y;                    \
    dst[6] = (__bf16)w1.z; dst[7] = (__bf16)w1.w;

// ---------------- embed + bf16 fragment pack of [x ; h_hi ; h_lo]
__global__ void k_embed(const int* __restrict__ seq, const float* __restrict__ emb,
                        const float* __restrict__ h0, __bf16* __restrict__ xhb)
{
    int b = blockIdx.x;
    int t = threadIdx.x;               // handles k = t*4 .. t*4+3
    int tok = seq[b];
    float4 xv = *(const float4*)(emb + (size_t)tok * Hd + t * 4);
    float4 hv = *(const float4*)(h0 + (size_t)b * Hd + t * 4);
    int kb = t >> 1, ko = (t & 1) * 4;
    __bf16* xp = xhb + (size_t)kb * 512 + b * 8 + ko;
    xp[0] = (__bf16)xv.x; xp[1] = (__bf16)xv.y;
    xp[2] = (__bf16)xv.z; xp[3] = (__bf16)xv.w;
    __bf16* hp = xhb + (size_t)(128 + kb) * 512 + b * 8 + ko;
    __bf16* lp = xhb + (size_t)(256 + kb) * 512 + b * 8 + ko;
    float h[4] = {hv.x, hv.y, hv.z, hv.w};
#pragma unroll
    for (int i = 0; i < 4; ++i) {
        __bf16 hi = (__bf16)h[i];
        hp[i] = hi;
        lp[i] = (__bf16)(h[i] - (float)hi);
    }
}

// ---------------- fused gates(MFMA, 8-wave K-split) + LSTM pointwise
// Block owns hh slice [hh0, hh0+4); its 16 MFMA rows = 4 gates x 4 hh.
// waves 0-3: x-part (plain bf16) k-windows of 256; waves 4-7: h-part (hi/lo).
// After LDS reduce: 256 threads do the LSTM cell and write h1/c1/catb.
__global__ void k_gates_lstm(const __bf16* __restrict__ xhb,
                             const float* __restrict__ W_ih, const float* __restrict__ W_hh,
                             const float* __restrict__ b_ih, const float* __restrict__ b_hh,
                             const float* __restrict__ c0,
                             float* __restrict__ h1o, float* __restrict__ c1o,
                             __bf16* __restrict__ catb)
{
    __shared__ float lds[8][64][20];
    __shared__ float gsum[16][66];
    int wave = threadIdx.x >> 6, lane = threadIdx.x & 63;
    int hh0 = blockIdx.x * 4;
    int rloc = lane & 15;                      // local row: gate g, hh offset
    int wrow = (rloc >> 2) * Hd + hh0 + (rloc & 3);
    int kq = lane >> 4;
    int isH = wave >> 2;
    int kbase = (wave & 3) * 256;

    const float* wp = (isH ? W_hh : W_ih) + (size_t)wrow * Hd + kbase + kq * 8;
    const __bf16* apx = xhb + rloc * 8;

    f32x4 acc[4] = {{0.f,0.f,0.f,0.f},{0.f,0.f,0.f,0.f},
                    {0.f,0.f,0.f,0.f},{0.f,0.f,0.f,0.f}};

    if (!isH) {
#pragma unroll 4
        for (int k0 = 0; k0 < 256; k0 += 32) {
            float4 w0 = *(const float4*)(wp + k0);
            float4 w1 = *(const float4*)(wp + k0 + 4);
            bf16x8 bf; CVT8(bf, w0, w1);
            int kb = ((kbase + k0) >> 3) + kq;
#pragma unroll
            for (int mt = 0; mt < 4; ++mt) {
                bf16x8 a = *(const bf16x8*)(apx + (size_t)kb * 512 + mt * 128);
                acc[mt] = __builtin_amdgcn_mfma_f32_16x16x32_bf16(a, bf, acc[mt], 0, 0, 0);
            }
        }
    } else {
#pragma unroll 2
        for (int k0 = 0; k0 < 256; k0 += 32) {
            float4 w0 = *(const float4*)(wp + k0);
            float4 w1 = *(const float4*)(wp + k0 + 4);
            bf16x8 bhi, blo;
            float wf[8] = {w0.x, w0.y, w0.z, w0.w, w1.x, w1.y, w1.z, w1.w};
#pragma unroll
            for (int i = 0; i < 8; ++i) {
                __bf16 hi = (__bf16)wf[i];
                bhi[i] = hi;
                blo[i] = (__bf16)(wf[i] - (float)hi);
            }
            int kb = ((kbase + k0) >> 3) + kq;
#pragma unroll
            for (int mt = 0; mt < 4; ++mt) {
                bf16x8 ahi = *(const bf16x8*)(apx + (size_t)(128 + kb) * 512 + mt * 128);
                bf16x8 alo = *(const bf16x8*)(apx + (size_t)(256 + kb) * 512 + mt * 128);
                acc[mt] = __builtin_amdgcn_mfma_f32_16x16x32_bf16(ahi, bhi, acc[mt], 0, 0, 0);
                acc[mt] = __builtin_amdgcn_mfma_f32_16x16x32_bf16(ahi, blo, acc[mt], 0, 0, 0);
                acc[mt] = __builtin_amdgcn_mfma_f32_16x16x32_bf16(alo, bhi, acc[mt], 0, 0, 0);
            }
        }
    }

#pragma unroll
    for (int mt = 0; mt < 4; ++mt)
        *(f32x4*)&lds[wave][lane][mt * 4] = acc[mt];
    __syncthreads();

    if (wave < 4) {
        int mt = wave;
        float bv = b_ih[wrow] + b_hh[wrow];
#pragma unroll
        for (int r = 0; r < 4; ++r) {
            float s = 0.f;
#pragma unroll
            for (int w = 0; w < 8; ++w) s += lds[w][lane][mt * 4 + r];
            int m = mt * 16 + kq * 4 + r;       // batch
            gsum[rloc][m] = s + bv;
        }
    }
    __syncthreads();

    int t = threadIdx.x;
    if (t < 256) {
        int b = t & 63, hl = t >> 6;
        int hh = hh0 + hl;
        float gi = gsum[0 + hl][b];
        float gf = gsum[4 + hl][b];
        float gg = gsum[8 + hl][b];
        float go = gsum[12 + hl][b];
        float c  = c0[(size_t)b * Hd + hh];
        float c1 = sigm(gf) * c + sigm(gi) * tanhf(gg);
        float h1 = sigm(go) * tanhf(c1);
        h1o[(size_t)b * Hd + hh] = h1;
        c1o[(size_t)b * Hd + hh] = c1;
        catb[(size_t)(hh >> 3) * 512 + b * 8 + (hh & 7)] = (__bf16)h1;
    }
}

// ---------------- fused energies + online-softmax context partials (one enc pass)
// 2 l-rows per wave-iteration: deeper load pipeline, interleaved shfl chains.
__global__ void k_attn_part(const float* __restrict__ enc, const float* __restrict__ h1,
                            float* __restrict__ energy, float* __restrict__ part)
{
    int chunk = blockIdx.x, b = blockIdx.y;
    int wave = threadIdx.x >> 6, lane = threadIdx.x & 63;

    float4 qv[4], ctx[4];
#pragma unroll
    for (int q = 0; q < 4; ++q) {
        qv[q] = *(const float4*)(h1 + (size_t)b * Hd + q * 256 + lane * 4);
        ctx[q] = make_float4(0.f, 0.f, 0.f, 0.f);
    }
    float m = -INFINITY, s = 0.f;

    for (int i = 0; i < LCHUNK / 8; ++i) {
        int l = chunk * LCHUNK + i * 8 + wave * 2;
        const float* ep0 = enc + ((size_t)l * B + b) * Hd;
        const float* ep1 = ep0 + (size_t)B * Hd;
        float4 ev0[4], ev1[4];
#pragma unroll
        for (int q = 0; q < 4; ++q) ev0[q] = *(const float4*)(ep0 + q * 256 + lane * 4);
#pragma unroll
        for (int q = 0; q < 4; ++q) ev1[q] = *(const float4*)(ep1 + q * 256 + lane * 4);

        float d0 = 0.f, d1 = 0.f;
#pragma unroll
        for (int q = 0; q < 4; ++q) {
            d0 += ev0[q].x * qv[q].x + ev0[q].y * qv[q].y
                + ev0[q].z * qv[q].z + ev0[q].w * qv[q].w;
            d1 += ev1[q].x * qv[q].x + ev1[q].y * qv[q].y
                + ev1[q].z * qv[q].z + ev1[q].w * qv[q].w;
        }
#pragma unroll
        for (int off = 32; off >= 1; off >>= 1) {
            d0 += __shfl_xor(d0, off);
            d1 += __shfl_xor(d1, off);
        }
        if (lane == 0) {
            energy[(size_t)b * Lw + l] = d0;
            energy[(size_t)b * Lw + l + 1] = d1;
        }

        float mn = fmaxf(d0, d1);
        if (mn > m) {                          // wave-uniform
            float sc = expf(m - mn);
            s *= sc;
#pragma unroll
            for (int q = 0; q < 4; ++q) {
                ctx[q].x *= sc; ctx[q].y *= sc; ctx[q].z *= sc; ctx[q].w *= sc;
            }
            m = mn;
        }
        float w0 = expf(d0 - m), w1 = expf(d1 - m);
        s += w0 + w1;
#pragma unroll
        for (int q = 0; q < 4; ++q) {
            ctx[q].x += w0 * ev0[q].x + w1 * ev1[q].x;
            ctx[q].y += w0 * ev0[q].y + w1 * ev1[q].y;
            ctx[q].z += w0 * ev0[q].z + w1 * ev1[q].z;
            ctx[q].w += w0 * ev0[q].w + w1 * ev1[q].w;
        }
    }

    // combine the 4 waves of this block
    __shared__ float lctx[4][Hd];
    __shared__ float lms[4][2];
#pragma unroll
    for (int q = 0; q < 4; ++q)
        *(float4*)(&lctx[wave][q * 256 + lane * 4]) = ctx[q];
    if (lane == 0) { lms[wave][0] = m; lms[wave][1] = s; }
    __syncthreads();

    float mb = fmaxf(fmaxf(lms[0][0], lms[1][0]), fmaxf(lms[2][0], lms[3][0]));
    float sc0 = expf(lms[0][0] - mb), sc1 = expf(lms[1][0] - mb);
    float sc2 = expf(lms[2][0] - mb), sc3 = expf(lms[3][0] - mb);
    float sb = lms[0][1] * sc0 + lms[1][1] * sc1 + lms[2][1] * sc2 + lms[3][1] * sc3;

    int t = threadIdx.x;
    float* pb = part + (size_t)(chunk * B + b) * PSTRIDE;
    float4 a0 = *(float4*)(&lctx[0][t * 4]);
    float4 a1 = *(float4*)(&lctx[1][t * 4]);
    float4 a2 = *(float4*)(&lctx[2][t * 4]);
    float4 a3 = *(float4*)(&lctx[3][t * 4]);
    float4 v;
    v.x = a0.x * sc0 + a1.x * sc1 + a2.x * sc2 + a3.x * sc3;
    v.y = a0.y * sc0 + a1.y * sc1 + a2.y * sc2 + a3.y * sc3;
    v.z = a0.z * sc0 + a1.z * sc1 + a2.z * sc2 + a3.z * sc3;
    v.w = a0.w * sc0 + a1.w * sc1 + a2.w * sc2 + a3.w * sc3;
    *(float4*)(pb + t * 4) = v;
    if (t == 0) { pb[1024] = mb; pb[1025] = sb; }
}

// ---------------- merge partials -> ctx (bf16 pack) + attn output normalize
__global__ void k_attn_combine(const float* __restrict__ part,
                               const float* __restrict__ energy,
                               __bf16* __restrict__ catb, float* __restrict__ attn)
{
    int b = blockIdx.x, t = threadIdx.x;
    float m = -INFINITY;
#pragma unroll
    for (int c = 0; c < NCHUNK; ++c)
        m = fmaxf(m, part[(size_t)(c * B + b) * PSTRIDE + 1024]);
    float s = 0.f, scl[NCHUNK];
#pragma unroll
    for (int c = 0; c < NCHUNK; ++c) {
        const float* pb = part + (size_t)(c * B + b) * PSTRIDE;
        scl[c] = expf(pb[1024] - m);
        s += pb[1025] * scl[c];
    }
    float4 v = make_float4(0.f, 0.f, 0.f, 0.f);
#pragma unroll
    for (int c = 0; c < NCHUNK; ++c) {
        float4 p = *(const float4*)(part + (size_t)(c * B + b) * PSTRIDE + t * 4);
        v.x += p.x * scl[c]; v.y += p.y * scl[c]; v.z += p.z * scl[c]; v.w += p.w * scl[c];
    }
    float inv = 1.f / s;
    v.x *= inv; v.y *= inv; v.z *= inv; v.w *= inv;
    int k = 1024 + t * 4;                                   // ctx k index
    __bf16* cp = catb + (size_t)(k >> 3) * 512 + b * 8 + (k & 7);
    cp[0] = (__bf16)v.x; cp[1] = (__bf16)v.y;
    cp[2] = (__bf16)v.z; cp[3] = (__bf16)v.w;

#pragma unroll
    for (int j = 0; j < 8; ++j) {
        int l = t + j * 256;
        attn[(size_t)b * Lw + l] = expf(energy[(size_t)b * Lw + l] - m) * inv;
    }
}

// ---------------- concat_out via bf16 MFMA, K-split over 8 waves (LDS reduce)
__global__ void k_concat_mfma(const __bf16* __restrict__ catb,
                              const float* __restrict__ W, const float* __restrict__ bias,
                              __bf16* __restrict__ conc)
{
    __shared__ float lds[8][64][20];
    int wave = threadIdx.x >> 6, lane = threadIdx.x & 63;
    int n0 = blockIdx.x * 16;
    int nl = n0 + (lane & 15);
    int kq = lane >> 4;
    int kbase = wave * 256;            // 8 waves x 256 = K=2048

    const float* wp = W + (size_t)nl * (2 * Hd) + kbase + kq * 8;
    const __bf16* ap = catb + (lane & 15) * 8;

    f32x4 acc[4] = {{0.f,0.f,0.f,0.f},{0.f,0.f,0.f,0.f},
                    {0.f,0.f,0.f,0.f},{0.f,0.f,0.f,0.f}};

#pragma unroll 4
    for (int k0 = 0; k0 < 256; k0 += 32) {
        float4 w0 = *(const float4*)(wp + k0);
        float4 w1 = *(const float4*)(wp + k0 + 4);
        bf16x8 bf; CVT8(bf, w0, w1);
        int kb = ((kbase + k0) >> 3) + kq;
#pragma unroll
        for (int mt = 0; mt < 4; ++mt) {
            bf16x8 a = *(const bf16x8*)(ap + (size_t)kb * 512 + mt * 128);
            acc[mt] = __builtin_amdgcn_mfma_f32_16x16x32_bf16(a, bf, acc[mt], 0, 0, 0);
        }
    }

#pragma unroll
    for (int mt = 0; mt < 4; ++mt)
        *(f32x4*)&lds[wave][lane][mt * 4] = acc[mt];
    __syncthreads();

    if (wave < 4) {
        int mt = wave;
        float bv = bias[nl];
#pragma unroll
        for (int r = 0; r < 4; ++r) {
            float s = 0.f;
#pragma unroll
            for (int w = 0; w < 8; ++w) s += lds[w][lane][mt * 4 + r];
            int m = mt * 16 + kq * 4 + r;       // batch
            conc[(size_t)(nl >> 3) * 512 + m * 8 + (nl & 7)] = (__bf16)tanhf(s + bv);
        }
    }
}

// ---------------- vocab projection via bf16 MFMA 16x16x32
__global__ void k_vocab_mfma(const __bf16* __restrict__ apack,
                             const float* __restrict__ W,
                             const float* __restrict__ bias,
                             float* __restrict__ out)
{
    int wave = threadIdx.x >> 6;
    int lane = threadIdx.x & 63;
    int n0 = (blockIdx.x * 4 + wave) * 16;
    if (n0 > Vd - 16) n0 = Vd - 16;        // tail shift-down (dup writes benign)

    int nl = n0 + (lane & 15);
    int kq = lane >> 4;
    const float* wp = W + (size_t)nl * Hd + kq * 8;
    const __bf16* ap = apack + (size_t)(lane & 15) * 8;

    f32x4 acc[4] = {{0.f,0.f,0.f,0.f},{0.f,0.f,0.f,0.f},
                    {0.f,0.f,0.f,0.f},{0.f,0.f,0.f,0.f}};

#pragma unroll 4
    for (int k0 = 0; k0 < Hd; k0 += 32) {
        float4 w0 = *(const float4*)(wp + k0);
        float4 w1 = *(const float4*)(wp + k0 + 4);
        bf16x8 bf; CVT8(bf, w0, w1);
        int kb = (k0 >> 3) + kq;
#pragma unroll
        for (int mt = 0; mt < 4; ++mt) {
            bf16x8 afrag = *(const bf16x8*)(ap + (size_t)kb * 512 + mt * 128);
            acc[mt] = __builtin_amdgcn_mfma_f32_16x16x32_bf16(afrag, bf, acc[mt], 0, 0, 0);
        }
    }

    float bv = bias[nl];
#pragma unroll
    for (int mt = 0; mt < 4; ++mt)
#pragma unroll
        for (int r = 0; r < 4; ++r) {
            int m = mt * 16 + (lane >> 4) * 4 + r;   // batch (C/D row)
            out[(size_t)m * Vd + nl] = acc[mt][r] + bv;
        }
}

extern "C" void kernel_launch(void* const* d_in, const int* in_sizes, int n_in,
                              void* d_out, int out_size, void* d_ws, size_t ws_size,
                              hipStream_t stream)
{
    const int*   seq    = (const int*)d_in[0];
    const float* enc    = (const float*)d_in[1];
    const float* h0     = (const float*)d_in[2];
    const float* c0     = (const float*)d_in[3];
    const float* emb    = (const float*)d_in[4];
    const float* W_ih   = (const float*)d_in[5];
    const float* W_hh   = (const float*)d_in[6];
    const float* b_ih   = (const float*)d_in[7];
    const float* b_hh   = (const float*)d_in[8];
    const float* W_cat  = (const float*)d_in[9];
    const float* b_cat  = (const float*)d_in[10];
    const float* W_out  = (const float*)d_in[11];
    const float* b_out  = (const float*)d_in[12];
    float* out = (float*)d_out;
    float* ws  = (float*)d_ws;

    __bf16* xhb    = (__bf16*)(ws + WS_XHB);
    __bf16* catb   = (__bf16*)(ws + WS_CATB);
    float*  energy = ws + WS_ENERGY;
    float*  part   = ws + WS_PART;
    __bf16* conc   = (__bf16*)(ws + WS_CONC);

    k_embed<<<B, 256, 0, stream>>>(seq, emb, h0, xhb);
    // fused gates+LSTM: 256 blocks (4 hh each) x 512 threads
    k_gates_lstm<<<256, 512, 0, stream>>>(xhb, W_ih, W_hh, b_ih, b_hh, c0,
                                          out + OUT_H1, out + OUT_C1, catb);
    k_attn_part<<<dim3(NCHUNK, B), 256, 0, stream>>>(enc, out + OUT_H1, energy, part);
    k_attn_combine<<<B, 256, 0, stream>>>(part, energy, catb, out + OUT_ATTN);
    // concat: 64 blocks x 512 threads (8-way K-split)
    k_concat_mfma<<<64, 512, 0, stream>>>(catb, W_cat, b_cat, conc);
    // vocab: N=50257 rows -> 786 blocks
    k_vocab_mfma<<<786, 256, 0, stream>>>(conc, W_out, b_out, out);
}